// Round 12
// baseline (540.209 us; speedup 1.0000x reference)
//
#include <hip/hip_runtime.h>

#define C 16
#define NIMG 24
#define H 96
#define W 192
#define PX (H*W)            // 18432
#define LOG2E 1.44269504088896f

typedef float v2f  __attribute__((ext_vector_type(2)));
typedef float v4f  __attribute__((ext_vector_type(4)));
typedef float v16f __attribute__((ext_vector_type(16)));
typedef short v8s  __attribute__((ext_vector_type(8)));

// workspace float offsets
#define QP_OFF 0                                // float2 [n][px]
#define KP_OFF (NIMG*PX*2)                      // float2 [n][px]
#define VP_OFF (2*NIMG*PX*2)                    // float4 [n][h][c4][w]
#define CMAX_OFF (VP_OFF + NIMG*PX*C)           // 8847360
#define RMAX_OFF (CMAX_OFF + NIMG*2*W)          // 8856576
#define SC_OFF   (RMAX_OFF + NIMG*2*H)          // 8861184  float s_col [n][h][w]
#define ACC_OFF  (SC_OFF + NIMG*PX)             // 9303552  ushort accC [n][h][c][w]
// end: 9303552 + 3538944 floats = 12842496 floats (~51.4 MB)

__device__ __forceinline__ short f2bf(float x) {
    union { float f; unsigned u; } v; v.f = x;
    unsigned r = v.u + 0x7fffu + ((v.u >> 16) & 1u);   // RNE
    return (short)(r >> 16);
}
__device__ __forceinline__ float bf2f(unsigned short u) {
    union { unsigned u; float f; } v; v.u = ((unsigned)u) << 16;
    return v.f;
}

__global__ __launch_bounds__(256)
void qkv_kernel(const float* __restrict__ x, long xn_s, long xc_s,
                const float* __restrict__ qw, const float* __restrict__ qb,
                const float* __restrict__ kw, const float* __restrict__ kb,
                const float* __restrict__ vw, const float* __restrict__ vb,
                float2* __restrict__ Qp, float2* __restrict__ Kp,
                float4* __restrict__ Vp)
{
    __shared__ float wq[2*C+2], wk[2*C+2], wv[C*C+C];
    int tid = threadIdx.x;
    if (tid < 2*C) { wq[tid] = qw[tid]; wk[tid] = kw[tid]; }
    if (tid < 2)   { wq[2*C+tid] = qb[tid]; wk[2*C+tid] = kb[tid]; }
    if (tid < C*C) wv[tid] = vw[tid];
    if (tid < C)   wv[C*C+tid] = vb[tid];
    __syncthreads();

    int id = blockIdx.x*256 + tid;        // 0 .. 442367
    int n  = id / PX;
    int p  = id - n*PX;
    int h  = p / W;
    int w  = p - h*W;
    const float* xp = x + (long)n*xn_s + p;

    float xv[C];
    #pragma unroll
    for (int c = 0; c < C; c++) xv[c] = xp[(long)c*xc_s];

    float q0 = wq[2*C], q1 = wq[2*C+1];
    float k0 = wk[2*C], k1 = wk[2*C+1];
    #pragma unroll
    for (int c = 0; c < C; c++) {
        q0 += wq[c]*xv[c];   q1 += wq[C+c]*xv[c];
        k0 += wk[c]*xv[c];   k1 += wk[C+c]*xv[c];
    }
    Qp[id] = make_float2(q0, q1);
    Kp[id] = make_float2(k0, k1);

    float vv[C];
    #pragma unroll
    for (int o = 0; o < C; o++) {
        float a = wv[C*C+o];
        #pragma unroll
        for (int c = 0; c < C; c++) a += wv[o*C+c]*xv[c];
        vv[o] = a;
    }
    #pragma unroll
    for (int c4 = 0; c4 < 4; c4++)
        Vp[(((long)n*H + h)*4 + c4)*W + w] =
            make_float4(vv[c4*4+0], vv[c4*4+1], vv[c4*4+2], vv[c4*4+3]);
}

__global__ __launch_bounds__(192)
void stats_kernel(const float2* __restrict__ Kp,
                  float* __restrict__ cmax, float* __restrict__ rmax)
{
    int n = blockIdx.x;
    int tid = threadIdx.x;
    const float2* Kpn = Kp + n*PX;

    float c0 = 0.f, c1 = 0.f;
    for (int h = 0; h < H; h++) {
        float2 k = Kpn[h*W + tid];
        c0 = fmaxf(c0, fabsf(k.x));
        c1 = fmaxf(c1, fabsf(k.y));
    }
    cmax[n*2*W + tid]     = c0;
    cmax[n*2*W + W + tid] = c1;

    if (tid < H) {
        float r0 = 0.f, r1 = 0.f;
        for (int j = 0; j < W; j++) {
            float2 k = Kpn[tid*W + j];
            r0 = fmaxf(r0, fabsf(k.x));
            r1 = fmaxf(r1, fabsf(k.y));
        }
        rmax[n*2*H + tid]     = r0;
        rmax[n*2*H + H + tid] = r1;
    }
}

// Column (H) attention: per-pixel VALU loop over 96 column entries, diag masked.
// Writes UNNORMALIZED partial acc (bf16) and partial sum s (fp32).
__global__ __launch_bounds__(384)
void col_attn_kernel(const float2* __restrict__ Qp, const float2* __restrict__ Kp,
                     const v4f* __restrict__ Vp,
                     const float* __restrict__ cmax, const float* __restrict__ rmax,
                     unsigned short* __restrict__ accC, float* __restrict__ sC)
{
    const int chunk = (NIMG*(H/2)) / 8;   // 144 ; 1152 % 8 == 0 -> bijective
    int bid = blockIdx.x;
    int swz = (bid & 7)*chunk + (bid >> 3);
    int n   = swz / (H/2);
    int h0  = (swz - n*(H/2)) * 2;
    int tid = threadIdx.x;
    int r   = tid / 192;
    int w   = tid - r*192;
    int hr  = h0 + r;

    const float2* Qpn = Qp + n*PX;
    const float2* Kpn = Kp + n*PX;
    const v4f*    Vpn = Vp + (long)n*PX*4;

    float2 qq = Qpn[hr*W + w];
    float qx = qq.x * LOG2E, qy = qq.y * LOG2E;
    float c0 = cmax[n*2*W + w], c1 = cmax[n*2*W + W + w];
    float r0 = rmax[n*2*H + hr], r1 = rmax[n*2*H + H + hr];
    float ax = fabsf(qx), ay = fabsf(qy);
    float m = fmaxf(ax*c0 + ay*c1, ax*r0 + ay*r1);

    v4f acc[4] = {};
    float s = 0.f;
    const float2* kp = Kpn + w;
    const v4f*    vp = Vpn + w;
    #pragma unroll 2
    for (int j = 0; j < H; j++) {
        float2 k = *kp;
        v4f a0 = vp[0*W], a1 = vp[1*W], a2 = vp[2*W], a3 = vp[3*W];
        float e = qx*k.x + qy*k.y;
        float p = __builtin_amdgcn_exp2f(e - m);
        p = (j == hr) ? 0.0f : p;
        s += p;
        acc[0] += a0*p; acc[1] += a1*p; acc[2] += a2*p; acc[3] += a3*p;
        kp += W; vp += 4*W;
    }
    sC[((long)n*H + hr)*W + w] = s;
    #pragma unroll
    for (int c = 0; c < C; c++)
        accC[(((long)n*H + hr)*16 + c)*W + w] = (unsigned short)f2bf(acc[c>>2][c&3]);
}

// Row (W) attention as MFMA: wave owns (n, h, half). D[16c x 16w] tiles,
// A = V_row fragments (c = lane&15, j = kc*32 + (lane>>4)*8 + e),
// B = P fragments built in-register with the SAME slot->k convention.
// Finalizes: (acc_row + acc_col)/(s_row + s_col)*gamma + residual.
__global__ __launch_bounds__(256, 4)
void row_attn_kernel(const float2* __restrict__ Qp, const float2* __restrict__ Kp,
                     const v4f* __restrict__ Vp,
                     const float* __restrict__ cmax, const float* __restrict__ rmax,
                     const unsigned short* __restrict__ accC, const float* __restrict__ sC,
                     const float* __restrict__ xres, long xn_s, long xc_s,
                     float* __restrict__ out, long on_s, long oc_s,
                     const float* __restrict__ gamma_p)
{
    const int chunk = (NIMG*(H/2)) / 8;   // 144
    int bid = blockIdx.x;
    int swz = (bid & 7)*chunk + (bid >> 3);
    int wid  = swz*4 + (int)(threadIdx.x >> 6);   // 0..4607 = (n,h,half)
    int lane = threadIdx.x & 63;
    int n    = wid / (H*2);
    int rem  = wid - n*(H*2);
    int h    = rem >> 1;
    int half = rem & 1;
    int li   = lane & 15;
    int g    = lane >> 4;

    const float2* Qpn = Qp + n*PX;
    const float*  Kf  = (const float*)(Kp + n*PX) + (long)h*W*2;       // kx,ky pairs of row h
    const float*  Arow = (const float*)Vp + ((((long)n*H + h)*4 + (li>>2))*W)*4; // c4 plane of row h
    int ci = li & 3;

    // per-wtile q (log2 domain) and shift bound m — formula identical to col kernel
    float r0 = rmax[n*2*H + h], r1 = rmax[n*2*H + H + h];
    float qx[6], qy[6], mW[6];
    #pragma unroll
    for (int t = 0; t < 6; t++) {
        int w = (half*6 + t)*16 + li;
        float2 qq = Qpn[h*W + w];
        float c0 = cmax[n*2*W + w], c1 = cmax[n*2*W + W + w];
        float lqx = qq.x * LOG2E, lqy = qq.y * LOG2E;
        float ax = fabsf(lqx), ay = fabsf(lqy);
        qx[t] = lqx; qy[t] = lqy;
        mW[t] = fmaxf(ax*c0 + ay*c1, ax*r0 + ay*r1);
    }

    v4f acc[6] = {};
    float sp[6] = {0.f,0.f,0.f,0.f,0.f,0.f};

    #pragma unroll
    for (int kc = 0; kc < 6; kc++) {
        int j0 = kc*32 + g*8;
        v16f kk = *(const v16f*)(Kf + (long)j0*2);        // j0..j0+7 (kx,ky)
        v16f A0 = *(const v16f*)(Arow + (long)j0*4);      // j0..j0+3 float4s
        v16f A1 = *(const v16f*)(Arow + (long)j0*4 + 16); // j0+4..j0+7
        v8s af;
        af[0]=f2bf(A0[0+ci]); af[1]=f2bf(A0[4+ci]); af[2]=f2bf(A0[8+ci]); af[3]=f2bf(A0[12+ci]);
        af[4]=f2bf(A1[0+ci]); af[5]=f2bf(A1[4+ci]); af[6]=f2bf(A1[8+ci]); af[7]=f2bf(A1[12+ci]);
        #pragma unroll
        for (int t = 0; t < 6; t++) {
            v8s bf;
            float sl = sp[t];
            #pragma unroll
            for (int e = 0; e < 8; e++) {
                float ev = qx[t]*kk[2*e] + qy[t]*kk[2*e+1];
                float p = __builtin_amdgcn_exp2f(ev - mW[t]);
                sl += p;
                bf[e] = f2bf(p);
            }
            sp[t] = sl;
            acc[t] = __builtin_amdgcn_mfma_f32_16x16x32_bf16(af, bf, acc[t], 0, 0, 0);
        }
    }

    // s: sum partials across the 4 k-groups (lanes li, li+16, li+32, li+48)
    #pragma unroll
    for (int t = 0; t < 6; t++) {
        float s = sp[t];
        s += __shfl_xor(s, 16);
        s += __shfl_xor(s, 32);
        sp[t] = s;
    }

    float gam = gamma_p[0];
    #pragma unroll
    for (int t = 0; t < 6; t++) {
        int w = (half*6 + t)*16 + li;
        float st = sC[((long)n*H + h)*W + w] + sp[t];
        float inv = 1.0f / st;
        #pragma unroll
        for (int rr = 0; rr < 4; rr++) {
            int c = g*4 + rr;   // D: row = (lane>>4)*4 + reg  [guide-verified]
            float ac = bf2f(accC[(((long)n*H + h)*16 + c)*W + w]);
            float tot = (acc[t][rr] + ac) * inv;
            long po = (long)h*W + w;
            out[(long)n*on_s + (long)c*oc_s + po] =
                gam*tot + xres[(long)n*xn_s + (long)c*xc_s + po];
        }
    }
}

extern "C" void kernel_launch(void* const* d_in, const int* in_sizes, int n_in,
                              void* d_out, int out_size, void* d_ws, size_t ws_size,
                              hipStream_t stream) {
    const float* cost = (const float*)d_in[0];   // (1,16,24,96,192)
    const float* q_w  = (const float*)d_in[1];
    const float* q_b  = (const float*)d_in[2];
    const float* k_w  = (const float*)d_in[3];
    const float* k_b  = (const float*)d_in[4];
    const float* v_w  = (const float*)d_in[5];
    const float* v_b  = (const float*)d_in[6];
    const float* gamma= (const float*)d_in[7];
    float* out = (float*)d_out;
    float* ws  = (float*)d_ws;

    float2* Qp = (float2*)(ws + QP_OFF);
    float2* Kp = (float2*)(ws + KP_OFF);
    float4* Vp = (float4*)(ws + VP_OFF);
    float*  cm = ws + CMAX_OFF;
    float*  rm = ws + RMAX_OFF;
    float*  sC = ws + SC_OFF;
    unsigned short* aC = (unsigned short*)(ws + ACC_OFF);

    const int qkv_blocks = (NIMG*PX)/256;   // 1728
    const int cr_blocks  = NIMG*(H/2);      // 1152

    // ---- pass 1: x = cost_volume [c][n][h][w] (n stride PX, c stride 24*PX) ----
    qkv_kernel<<<qkv_blocks, 256, 0, stream>>>(
        cost, (long)PX, (long)NIMG*PX,
        q_w, q_b, k_w, k_b, v_w, v_b, Qp, Kp, Vp);
    stats_kernel<<<NIMG, 192, 0, stream>>>(Kp, cm, rm);
    col_attn_kernel<<<cr_blocks, 384, 0, stream>>>(
        Qp, Kp, (const v4f*)Vp, cm, rm, aC, sC);
    // pass-1 intermediate lives in d_out with FINAL [c][n][h][w] strides
    row_attn_kernel<<<cr_blocks, 256, 0, stream>>>(
        Qp, Kp, (const v4f*)Vp, cm, rm, aC, sC,
        cost, (long)PX, (long)NIMG*PX,
        out,  (long)PX, (long)NIMG*PX,
        gamma);

    // ---- pass 2: x = d_out (same strides) ----
    qkv_kernel<<<qkv_blocks, 256, 0, stream>>>(
        out, (long)PX, (long)NIMG*PX,
        q_w, q_b, k_w, k_b, v_w, v_b, Qp, Kp, Vp);
    stats_kernel<<<NIMG, 192, 0, stream>>>(Kp, cm, rm);
    col_attn_kernel<<<cr_blocks, 384, 0, stream>>>(
        Qp, Kp, (const v4f*)Vp, cm, rm, aC, sC);
    // reads xres==out and writes out at the SAME element per thread (safe RMW)
    row_attn_kernel<<<cr_blocks, 256, 0, stream>>>(
        Qp, Kp, (const v4f*)Vp, cm, rm, aC, sC,
        out, (long)PX, (long)NIMG*PX,
        out, (long)PX, (long)NIMG*PX,
        gamma);
}

// Round 13
// 365.007 us; speedup vs baseline: 1.4800x; 1.4800x over previous
//
#include <hip/hip_runtime.h>

#define C 16
#define NIMG 24
#define H 96
#define W 192
#define PX (H*W)            // 18432
#define LOG2E 1.44269504088896f

typedef float v2f  __attribute__((ext_vector_type(2)));
typedef float v4f  __attribute__((ext_vector_type(4)));
typedef short v8s  __attribute__((ext_vector_type(8)));

// workspace float offsets
#define QP_OFF 0                                // float2 [n][px]
#define KP_OFF (NIMG*PX*2)                      // float2 [n][px]
#define VP_OFF (2*NIMG*PX*2)                    // float4 [n][h][c4][w]
#define CMAX_OFF (VP_OFF + NIMG*PX*C)           // 8847360
#define RMAX_OFF (CMAX_OFF + NIMG*2*W)          // 8856576
#define SC_OFF   (RMAX_OFF + NIMG*2*H)          // 8861184  float s_col [n][h][w]
#define ACC_OFF  (SC_OFF + NIMG*PX)             // 9303552  ushort accC [n][h][c][w]

__device__ __forceinline__ short f2bf(float x) {
    union { float f; unsigned u; } v; v.f = x;
    unsigned r = v.u + 0x7fffu + ((v.u >> 16) & 1u);   // RNE
    return (short)(r >> 16);
}
__device__ __forceinline__ float bf2f(unsigned short u) {
    union { unsigned u; float f; } v; v.u = ((unsigned)u) << 16;
    return v.f;
}

__global__ __launch_bounds__(256)
void qkv_kernel(const float* __restrict__ x, long xn_s, long xc_s,
                const float* __restrict__ qw, const float* __restrict__ qb,
                const float* __restrict__ kw, const float* __restrict__ kb,
                const float* __restrict__ vw, const float* __restrict__ vb,
                float2* __restrict__ Qp, float2* __restrict__ Kp,
                float4* __restrict__ Vp)
{
    __shared__ float wq[2*C+2], wk[2*C+2], wv[C*C+C];
    int tid = threadIdx.x;
    if (tid < 2*C) { wq[tid] = qw[tid]; wk[tid] = kw[tid]; }
    if (tid < 2)   { wq[2*C+tid] = qb[tid]; wk[2*C+tid] = kb[tid]; }
    if (tid < C*C) wv[tid] = vw[tid];
    if (tid < C)   wv[C*C+tid] = vb[tid];
    __syncthreads();

    int id = blockIdx.x*256 + tid;        // 0 .. 442367
    int n  = id / PX;
    int p  = id - n*PX;
    int h  = p / W;
    int w  = p - h*W;
    const float* xp = x + (long)n*xn_s + p;

    float xv[C];
    #pragma unroll
    for (int c = 0; c < C; c++) xv[c] = xp[(long)c*xc_s];

    float q0 = wq[2*C], q1 = wq[2*C+1];
    float k0 = wk[2*C], k1 = wk[2*C+1];
    #pragma unroll
    for (int c = 0; c < C; c++) {
        q0 += wq[c]*xv[c];   q1 += wq[C+c]*xv[c];
        k0 += wk[c]*xv[c];   k1 += wk[C+c]*xv[c];
    }
    Qp[id] = make_float2(q0, q1);
    Kp[id] = make_float2(k0, k1);

    float vv[C];
    #pragma unroll
    for (int o = 0; o < C; o++) {
        float a = wv[C*C+o];
        #pragma unroll
        for (int c = 0; c < C; c++) a += wv[o*C+c]*xv[c];
        vv[o] = a;
    }
    #pragma unroll
    for (int c4 = 0; c4 < 4; c4++)
        Vp[(((long)n*H + h)*4 + c4)*W + w] =
            make_float4(vv[c4*4+0], vv[c4*4+1], vv[c4*4+2], vv[c4*4+3]);
}

__global__ __launch_bounds__(192)
void stats_kernel(const float2* __restrict__ Kp,
                  float* __restrict__ cmax, float* __restrict__ rmax)
{
    int n = blockIdx.x;
    int tid = threadIdx.x;
    const float2* Kpn = Kp + n*PX;

    float c0 = 0.f, c1 = 0.f;
    for (int h = 0; h < H; h++) {
        float2 k = Kpn[h*W + tid];
        c0 = fmaxf(c0, fabsf(k.x));
        c1 = fmaxf(c1, fabsf(k.y));
    }
    cmax[n*2*W + tid]     = c0;
    cmax[n*2*W + W + tid] = c1;

    if (tid < H) {
        float r0 = 0.f, r1 = 0.f;
        for (int j = 0; j < W; j++) {
            float2 k = Kpn[tid*W + j];
            r0 = fmaxf(r0, fabsf(k.x));
            r1 = fmaxf(r1, fabsf(k.y));
        }
        rmax[n*2*H + tid]     = r0;
        rmax[n*2*H + H + tid] = r1;
    }
}

// Column (H) attention: 2 rows/thread, 4 rows/block (halves column L2 traffic).
// Writes UNNORMALIZED partial acc (bf16) and partial sum s (fp32).
__global__ __launch_bounds__(384)
void col_attn_kernel(const float2* __restrict__ Qp, const float2* __restrict__ Kp,
                     const v4f* __restrict__ Vp,
                     const float* __restrict__ cmax, const float* __restrict__ rmax,
                     unsigned short* __restrict__ accC, float* __restrict__ sC)
{
    const int chunk = (NIMG*(H/4)) / 8;   // 72 ; 576 % 8 == 0 -> bijective
    int bid = blockIdx.x;
    int swz = (bid & 7)*chunk + (bid >> 3);
    int n   = swz / (H/4);
    int h0  = (swz - n*(H/4)) * 4;
    int tid = threadIdx.x;
    int gi  = tid / 192;
    int w   = tid - gi*192;
    int hr0 = h0 + 2*gi;
    int hr1 = hr0 + 1;

    const float2* Qpn = Qp + n*PX;
    const float2* Kpn = Kp + n*PX;
    const v4f*    Vpn = Vp + (long)n*PX*4;

    float c0 = cmax[n*2*W + w], c1 = cmax[n*2*W + W + w];
    float qx0, qy0, m0, qx1, qy1, m1;
    {
        float2 qq = Qpn[hr0*W + w];
        qx0 = qq.x * LOG2E;  qy0 = qq.y * LOG2E;
        float r0 = rmax[n*2*H + hr0], r1 = rmax[n*2*H + H + hr0];
        m0 = fmaxf(fabsf(qx0)*c0 + fabsf(qy0)*c1, fabsf(qx0)*r0 + fabsf(qy0)*r1);
    }
    {
        float2 qq = Qpn[hr1*W + w];
        qx1 = qq.x * LOG2E;  qy1 = qq.y * LOG2E;
        float r0 = rmax[n*2*H + hr1], r1 = rmax[n*2*H + H + hr1];
        m1 = fmaxf(fabsf(qx1)*c0 + fabsf(qy1)*c1, fabsf(qx1)*r0 + fabsf(qy1)*r1);
    }

    v4f acc0[4] = {}, acc1[4] = {};
    float s0 = 0.f, s1 = 0.f;

    const float2* kp = Kpn + w;
    const v4f*    vp = Vpn + w;
    #pragma unroll 2
    for (int j = 0; j < H; j++) {
        float2 k = *kp;
        v4f a0 = vp[0*W], a1 = vp[1*W], a2 = vp[2*W], a3 = vp[3*W];
        float e0 = qx0*k.x + qy0*k.y;
        float p0 = __builtin_amdgcn_exp2f(e0 - m0);
        p0 = (j == hr0) ? 0.0f : p0;
        float e1 = qx1*k.x + qy1*k.y;
        float p1 = __builtin_amdgcn_exp2f(e1 - m1);
        p1 = (j == hr1) ? 0.0f : p1;
        s0 += p0;  s1 += p1;
        acc0[0] += a0*p0; acc0[1] += a1*p0; acc0[2] += a2*p0; acc0[3] += a3*p0;
        acc1[0] += a0*p1; acc1[1] += a1*p1; acc1[2] += a2*p1; acc1[3] += a3*p1;
        kp += W; vp += 4*W;
    }
    sC[((long)n*H + hr0)*W + w] = s0;
    sC[((long)n*H + hr1)*W + w] = s1;
    #pragma unroll
    for (int c = 0; c < C; c++)
        accC[(((long)n*H + hr0)*16 + c)*W + w] = (unsigned short)f2bf(acc0[c>>2][c&3]);
    #pragma unroll
    for (int c = 0; c < C; c++)
        accC[(((long)n*H + hr1)*16 + c)*W + w] = (unsigned short)f2bf(acc1[c>>2][c&3]);
}

// Row (W) attention as MFMA. Block = 2 rows; stages V (bf16) + K (fp32) in LDS.
// Wave (r, half) computes 6 D[16c x 16w] tiles via 6 k-chunks of 16x16x32 bf16 MFMA.
// A fragment: one ds_read_b128 per k-chunk (c = lane&15, j = kc*32+(lane>>4)*8+e).
// B fragment built in-register with the identical slot->k convention (R12-verified).
__global__ __launch_bounds__(256)
void row_attn_kernel(const float2* __restrict__ Qp, const float2* __restrict__ Kp,
                     const v4f* __restrict__ Vp,
                     const float* __restrict__ cmax, const float* __restrict__ rmax,
                     const unsigned short* __restrict__ accC, const float* __restrict__ sC,
                     const float* __restrict__ xres, long xn_s, long xc_s,
                     float* __restrict__ out, long on_s, long oc_s,
                     const float* __restrict__ gamma_p)
{
    __shared__ __align__(16) unsigned short Vl[2][16][200];  // bf16, pad 192->200
    __shared__ __align__(16) float          Kl[2][192][2];   // fp32 kx,ky

    const int chunk = (NIMG*(H/2)) / 8;   // 144
    int bid = blockIdx.x;
    int swz = (bid & 7)*chunk + (bid >> 3);
    int n   = swz / (H/2);
    int h0  = (swz - n*(H/2)) * 2;
    int tid = threadIdx.x;

    const float2* Qpn = Qp + n*PX;
    const float2* Kpn = Kp + n*PX;
    const v4f*    Vpn = Vp + (long)n*PX*4;

    // ---- stage: V 2 rows x 4 c4 x 192 w = 1536 float4s, 6 per thread ----
    #pragma unroll
    for (int i = 0; i < 6; i++) {
        int idx = i*256 + tid;            // 0..1535
        int rr  = idx / 768;              // 768 = 4*192
        int rem = idx - rr*768;
        int c4  = rem / 192;
        int w2  = rem - c4*192;
        v4f v = Vpn[((long)(h0+rr)*4 + c4)*W + w2];
        Vl[rr][c4*4+0][w2] = (unsigned short)f2bf(v[0]);
        Vl[rr][c4*4+1][w2] = (unsigned short)f2bf(v[1]);
        Vl[rr][c4*4+2][w2] = (unsigned short)f2bf(v[2]);
        Vl[rr][c4*4+3][w2] = (unsigned short)f2bf(v[3]);
    }
    if (tid < 384) {
        int rr = tid / 192, w2 = tid - rr*192;
        float2 kk = Kpn[(h0+rr)*W + w2];
        Kl[rr][w2][0] = kk.x;
        Kl[rr][w2][1] = kk.y;
    }

    int wv   = tid >> 6;        // 0..3
    int r    = wv >> 1;
    int half = wv & 1;
    int lane = tid & 63;
    int li   = lane & 15;
    int g    = lane >> 4;
    int h    = h0 + r;

    // per-wtile q (log2 domain) and shift bound m — identical formula to col kernel
    float r0 = rmax[n*2*H + h], r1 = rmax[n*2*H + H + h];
    float qx[6], qy[6], mW[6];
    #pragma unroll
    for (int t = 0; t < 6; t++) {
        int w = (half*6 + t)*16 + li;
        float2 qq = Qpn[h*W + w];
        float c0 = cmax[n*2*W + w], c1 = cmax[n*2*W + W + w];
        float lqx = qq.x * LOG2E, lqy = qq.y * LOG2E;
        qx[t] = lqx; qy[t] = lqy;
        mW[t] = fmaxf(fabsf(lqx)*c0 + fabsf(lqy)*c1, fabsf(lqx)*r0 + fabsf(lqy)*r1);
    }

    __syncthreads();

    v4f acc[6] = {};
    float sp[6] = {0.f,0.f,0.f,0.f,0.f,0.f};

    #pragma unroll
    for (int kc = 0; kc < 6; kc++) {
        int j0 = kc*32 + g*8;
        v8s af = *(const v8s*)&Vl[r][li][j0];                 // one ds_read_b128
        const v4f* kp4 = (const v4f*)&Kl[r][j0][0];
        v4f k0 = kp4[0], k1 = kp4[1], k2 = kp4[2], k3 = kp4[3];
        float kxv[8] = {k0[0],k0[2],k1[0],k1[2],k2[0],k2[2],k3[0],k3[2]};
        float kyv[8] = {k0[1],k0[3],k1[1],k1[3],k2[1],k2[3],k3[1],k3[3]};
        #pragma unroll
        for (int t = 0; t < 6; t++) {
            v8s bf;
            float sl = sp[t];
            #pragma unroll
            for (int e = 0; e < 8; e++) {
                float ev = qx[t]*kxv[e] + qy[t]*kyv[e];
                float p = __builtin_amdgcn_exp2f(ev - mW[t]);
                sl += p;
                bf[e] = f2bf(p);
            }
            sp[t] = sl;
            acc[t] = __builtin_amdgcn_mfma_f32_16x16x32_bf16(af, bf, acc[t], 0, 0, 0);
        }
    }

    float gam = gamma_p[0];
    #pragma unroll
    for (int t = 0; t < 6; t++) {
        float s = sp[t];
        s += __shfl_xor(s, 16);
        s += __shfl_xor(s, 32);
        int w = (half*6 + t)*16 + li;
        float st = sC[((long)n*H + h)*W + w] + s;
        float inv = 1.0f / st;
        long po = (long)h*W + w;
        #pragma unroll
        for (int rr = 0; rr < 4; rr++) {
            int c = g*4 + rr;   // D: row = (lane>>4)*4 + reg
            float ac = bf2f(accC[(((long)n*H + h)*16 + c)*W + w]);
            float tot = (acc[t][rr] + ac) * inv;
            out[(long)n*on_s + (long)c*oc_s + po] =
                gam*tot + xres[(long)n*xn_s + (long)c*xc_s + po];
        }
    }
}

extern "C" void kernel_launch(void* const* d_in, const int* in_sizes, int n_in,
                              void* d_out, int out_size, void* d_ws, size_t ws_size,
                              hipStream_t stream) {
    const float* cost = (const float*)d_in[0];   // (1,16,24,96,192)
    const float* q_w  = (const float*)d_in[1];
    const float* q_b  = (const float*)d_in[2];
    const float* k_w  = (const float*)d_in[3];
    const float* k_b  = (const float*)d_in[4];
    const float* v_w  = (const float*)d_in[5];
    const float* v_b  = (const float*)d_in[6];
    const float* gamma= (const float*)d_in[7];
    float* out = (float*)d_out;
    float* ws  = (float*)d_ws;

    float2* Qp = (float2*)(ws + QP_OFF);
    float2* Kp = (float2*)(ws + KP_OFF);
    float4* Vp = (float4*)(ws + VP_OFF);
    float*  cm = ws + CMAX_OFF;
    float*  rm = ws + RMAX_OFF;
    float*  sC = ws + SC_OFF;
    unsigned short* aC = (unsigned short*)(ws + ACC_OFF);

    const int qkv_blocks = (NIMG*PX)/256;   // 1728
    const int col_blocks = NIMG*(H/4);      // 576
    const int row_blocks = NIMG*(H/2);      // 1152

    // ---- pass 1: x = cost_volume [c][n][h][w] (n stride PX, c stride 24*PX) ----
    qkv_kernel<<<qkv_blocks, 256, 0, stream>>>(
        cost, (long)PX, (long)NIMG*PX,
        q_w, q_b, k_w, k_b, v_w, v_b, Qp, Kp, Vp);
    stats_kernel<<<NIMG, 192, 0, stream>>>(Kp, cm, rm);
    col_attn_kernel<<<col_blocks, 384, 0, stream>>>(
        Qp, Kp, (const v4f*)Vp, cm, rm, aC, sC);
    row_attn_kernel<<<row_blocks, 256, 0, stream>>>(
        Qp, Kp, (const v4f*)Vp, cm, rm, aC, sC,
        cost, (long)PX, (long)NIMG*PX,
        out,  (long)PX, (long)NIMG*PX,
        gamma);

    // ---- pass 2: x = d_out (same strides; per-thread same-element RMW is safe) ----
    qkv_kernel<<<qkv_blocks, 256, 0, stream>>>(
        out, (long)PX, (long)NIMG*PX,
        q_w, q_b, k_w, k_b, v_w, v_b, Qp, Kp, Vp);
    stats_kernel<<<NIMG, 192, 0, stream>>>(Kp, cm, rm);
    col_attn_kernel<<<col_blocks, 384, 0, stream>>>(
        Qp, Kp, (const v4f*)Vp, cm, rm, aC, sC);
    row_attn_kernel<<<row_blocks, 256, 0, stream>>>(
        Qp, Kp, (const v4f*)Vp, cm, rm, aC, sC,
        out, (long)PX, (long)NIMG*PX,
        out, (long)PX, (long)NIMG*PX,
        gamma);
}

// Round 15
// 255.913 us; speedup vs baseline: 2.1109x; 1.4263x over previous
//
#include <hip/hip_runtime.h>

#define C 16
#define NIMG 24
#define H 96
#define W 192
#define PX (H*W)            // 18432
#define LOG2E 1.44269504088896f

typedef float v2f  __attribute__((ext_vector_type(2)));
typedef float v4f  __attribute__((ext_vector_type(4)));
typedef short v8s  __attribute__((ext_vector_type(8)));

// workspace float offsets
#define QP_OFF 0                                // float2 [n][px]
#define KP_OFF (NIMG*PX*2)                      // float2 [n][px]
#define VP_OFF (2*NIMG*PX*2)                    // float4 [n][h][c4][w]
#define CMAX_OFF (VP_OFF + NIMG*PX*C)           // 8847360
#define RMAX_OFF (CMAX_OFF + NIMG*2*W)          // 8856576
#define SC_OFF   (RMAX_OFF + NIMG*2*H)          // 8861184  float s_col [n][h][w]
#define ACC_OFF  (SC_OFF + NIMG*PX)             // 9303552  ushort accC [n][h][c][w]

__device__ __forceinline__ short f2bf(float x) {
    union { float f; unsigned u; } v; v.f = x;
    unsigned r = v.u + 0x7fffu + ((v.u >> 16) & 1u);   // RNE
    return (short)(r >> 16);
}
__device__ __forceinline__ float bf2f(unsigned short u) {
    union { unsigned u; float f; } v; v.u = ((unsigned)u) << 16;
    return v.f;
}

__global__ __launch_bounds__(256)
void qkv_kernel(const float* __restrict__ x, long xn_s, long xc_s,
                const float* __restrict__ qw, const float* __restrict__ qb,
                const float* __restrict__ kw, const float* __restrict__ kb,
                const float* __restrict__ vw, const float* __restrict__ vb,
                float2* __restrict__ Qp, float2* __restrict__ Kp,
                float4* __restrict__ Vp)
{
    __shared__ float wq[2*C+2], wk[2*C+2], wv[C*C+C];
    int tid = threadIdx.x;
    if (tid < 2*C) { wq[tid] = qw[tid]; wk[tid] = kw[tid]; }
    if (tid < 2)   { wq[2*C+tid] = qb[tid]; wk[2*C+tid] = kb[tid]; }
    if (tid < C*C) wv[tid] = vw[tid];
    if (tid < C)   wv[C*C+tid] = vb[tid];
    __syncthreads();

    int id = blockIdx.x*256 + tid;        // 0 .. 442367
    int n  = id / PX;
    int p  = id - n*PX;
    int h  = p / W;
    int w  = p - h*W;
    const float* xp = x + (long)n*xn_s + p;

    float xv[C];
    #pragma unroll
    for (int c = 0; c < C; c++) xv[c] = xp[(long)c*xc_s];

    float q0 = wq[2*C], q1 = wq[2*C+1];
    float k0 = wk[2*C], k1 = wk[2*C+1];
    #pragma unroll
    for (int c = 0; c < C; c++) {
        q0 += wq[c]*xv[c];   q1 += wq[C+c]*xv[c];
        k0 += wk[c]*xv[c];   k1 += wk[C+c]*xv[c];
    }
    Qp[id] = make_float2(q0, q1);
    Kp[id] = make_float2(k0, k1);

    float vv[C];
    #pragma unroll
    for (int o = 0; o < C; o++) {
        float a = wv[C*C+o];
        #pragma unroll
        for (int c = 0; c < C; c++) a += wv[o*C+c]*xv[c];
        vv[o] = a;
    }
    #pragma unroll
    for (int c4 = 0; c4 < 4; c4++)
        Vp[(((long)n*H + h)*4 + c4)*W + w] =
            make_float4(vv[c4*4+0], vv[c4*4+1], vv[c4*4+2], vv[c4*4+3]);
}

__global__ __launch_bounds__(192)
void stats_kernel(const float2* __restrict__ Kp,
                  float* __restrict__ cmax, float* __restrict__ rmax)
{
    int n = blockIdx.x;
    int tid = threadIdx.x;
    const float2* Kpn = Kp + n*PX;

    float c0 = 0.f, c1 = 0.f;
    for (int h = 0; h < H; h++) {
        float2 k = Kpn[h*W + tid];
        c0 = fmaxf(c0, fabsf(k.x));
        c1 = fmaxf(c1, fabsf(k.y));
    }
    cmax[n*2*W + tid]     = c0;
    cmax[n*2*W + W + tid] = c1;

    if (tid < H) {
        float r0 = 0.f, r1 = 0.f;
        for (int j = 0; j < W; j++) {
            float2 k = Kpn[tid*W + j];
            r0 = fmaxf(r0, fabsf(k.x));
            r1 = fmaxf(r1, fabsf(k.y));
        }
        rmax[n*2*H + tid]     = r0;
        rmax[n*2*H + H + tid] = r1;
    }
}

// Column (H) attention: 2 rows/thread, 4 rows/block, manual 1-deep prefetch
// pipeline (loads for j+1 issued before computing j). Writes UNNORMALIZED
// partial acc (bf16) and partial sum s (fp32).
__global__ __launch_bounds__(384)
void col_attn_kernel(const float2* __restrict__ Qp, const float2* __restrict__ Kp,
                     const v4f* __restrict__ Vp,
                     const float* __restrict__ cmax, const float* __restrict__ rmax,
                     unsigned short* __restrict__ accC, float* __restrict__ sC)
{
    const int chunk = (NIMG*(H/4)) / 8;   // 72 ; 576 % 8 == 0 -> bijective
    int bid = blockIdx.x;
    int swz = (bid & 7)*chunk + (bid >> 3);
    int n   = swz / (H/4);
    int h0  = (swz - n*(H/4)) * 4;
    int tid = threadIdx.x;
    int gi  = tid / 192;
    int w   = tid - gi*192;
    int hr0 = h0 + 2*gi;
    int hr1 = hr0 + 1;

    const float2* Qpn = Qp + n*PX;
    const float2* Kpn = Kp + n*PX;
    const v4f*    Vpn = Vp + (long)n*PX*4;

    float c0 = cmax[n*2*W + w], c1 = cmax[n*2*W + W + w];
    float qx0, qy0, m0, qx1, qy1, m1;
    {
        float2 qq = Qpn[hr0*W + w];
        qx0 = qq.x * LOG2E;  qy0 = qq.y * LOG2E;
        float r0 = rmax[n*2*H + hr0], r1 = rmax[n*2*H + H + hr0];
        m0 = fmaxf(fabsf(qx0)*c0 + fabsf(qy0)*c1, fabsf(qx0)*r0 + fabsf(qy0)*r1);
    }
    {
        float2 qq = Qpn[hr1*W + w];
        qx1 = qq.x * LOG2E;  qy1 = qq.y * LOG2E;
        float r0 = rmax[n*2*H + hr1], r1 = rmax[n*2*H + H + hr1];
        m1 = fmaxf(fabsf(qx1)*c0 + fabsf(qy1)*c1, fabsf(qx1)*r0 + fabsf(qy1)*r1);
    }

    v4f acc0[4] = {}, acc1[4] = {};
    float s0 = 0.f, s1 = 0.f;

    const float2* kp = Kpn + w;
    const v4f*    vp = Vpn + w;

    // prologue: load j=0
    float2 kc = *kp;
    v4f b0 = vp[0*W], b1 = vp[1*W], b2 = vp[2*W], b3 = vp[3*W];

#define COL_STEP(J, KK, A0, A1, A2, A3) do {                                   \
        float e0 = qx0*(KK).x + qy0*(KK).y;                                    \
        float p0 = __builtin_amdgcn_exp2f(e0 - m0);                            \
        p0 = ((J) == hr0) ? 0.0f : p0;                                         \
        float e1 = qx1*(KK).x + qy1*(KK).y;                                    \
        float p1 = __builtin_amdgcn_exp2f(e1 - m1);                            \
        p1 = ((J) == hr1) ? 0.0f : p1;                                         \
        s0 += p0;  s1 += p1;                                                   \
        acc0[0] += (A0)*p0; acc0[1] += (A1)*p0; acc0[2] += (A2)*p0; acc0[3] += (A3)*p0; \
        acc1[0] += (A0)*p1; acc1[1] += (A1)*p1; acc1[2] += (A2)*p1; acc1[3] += (A3)*p1; \
    } while (0)

    for (int j = 0; j < H-1; j++) {
        // issue next-j loads first (5 loads in flight during compute)
        float2 kn = kp[W];
        v4f n0 = vp[4*W], n1 = vp[5*W], n2 = vp[6*W], n3 = vp[7*W];
        COL_STEP(j, kc, b0, b1, b2, b3);
        kc = kn; b0 = n0; b1 = n1; b2 = n2; b3 = n3;
        kp += W; vp += 4*W;
    }
    COL_STEP(H-1, kc, b0, b1, b2, b3);
#undef COL_STEP

    sC[((long)n*H + hr0)*W + w] = s0;
    sC[((long)n*H + hr1)*W + w] = s1;
    #pragma unroll
    for (int c = 0; c < C; c++)
        accC[(((long)n*H + hr0)*16 + c)*W + w] = (unsigned short)f2bf(acc0[c>>2][c&3]);
    #pragma unroll
    for (int c = 0; c < C; c++)
        accC[(((long)n*H + hr1)*16 + c)*W + w] = (unsigned short)f2bf(acc1[c>>2][c&3]);
}

// Row (W) attention as MFMA. Block = 2 rows; stages V (bf16) + K (fp32) in LDS.
// Wave (r, half) computes 6 D[16c x 16w] tiles via 6 k-chunks of 16x16x32 bf16 MFMA.
__global__ __launch_bounds__(256)
void row_attn_kernel(const float2* __restrict__ Qp, const float2* __restrict__ Kp,
                     const v4f* __restrict__ Vp,
                     const float* __restrict__ cmax, const float* __restrict__ rmax,
                     const unsigned short* __restrict__ accC, const float* __restrict__ sC,
                     const float* __restrict__ xres, long xn_s, long xc_s,
                     float* __restrict__ out, long on_s, long oc_s,
                     const float* __restrict__ gamma_p)
{
    __shared__ __align__(16) unsigned short Vl[2][16][200];  // bf16, pad 192->200
    __shared__ __align__(16) float          Kl[2][192][2];   // fp32 kx,ky

    const int chunk = (NIMG*(H/2)) / 8;   // 144
    int bid = blockIdx.x;
    int swz = (bid & 7)*chunk + (bid >> 3);
    int n   = swz / (H/2);
    int h0  = (swz - n*(H/2)) * 2;
    int tid = threadIdx.x;

    const float2* Qpn = Qp + n*PX;
    const float2* Kpn = Kp + n*PX;
    const v4f*    Vpn = Vp + (long)n*PX*4;

    // ---- stage: V 2 rows x 4 c4 x 192 w = 1536 float4s, 6 per thread ----
    #pragma unroll
    for (int i = 0; i < 6; i++) {
        int idx = i*256 + tid;            // 0..1535
        int rr  = idx / 768;              // 768 = 4*192
        int rem = idx - rr*768;
        int c4  = rem / 192;
        int w2  = rem - c4*192;
        v4f v = Vpn[((long)(h0+rr)*4 + c4)*W + w2];
        Vl[rr][c4*4+0][w2] = (unsigned short)f2bf(v[0]);
        Vl[rr][c4*4+1][w2] = (unsigned short)f2bf(v[1]);
        Vl[rr][c4*4+2][w2] = (unsigned short)f2bf(v[2]);
        Vl[rr][c4*4+3][w2] = (unsigned short)f2bf(v[3]);
    }
    // K staging: 256-thread block -> tid<192 threads each stage BOTH rows
    // (R13/R14 bug: a tid<384 guard left Kl[1][64..191] uninitialized -> NaN)
    if (tid < 192) {
        float2 ka = Kpn[(h0+0)*W + tid];
        float2 kb = Kpn[(h0+1)*W + tid];
        Kl[0][tid][0] = ka.x;  Kl[0][tid][1] = ka.y;
        Kl[1][tid][0] = kb.x;  Kl[1][tid][1] = kb.y;
    }

    int wv   = tid >> 6;        // 0..3
    int r    = wv >> 1;
    int half = wv & 1;
    int lane = tid & 63;
    int li   = lane & 15;
    int g    = lane >> 4;
    int h    = h0 + r;

    float r0 = rmax[n*2*H + h], r1 = rmax[n*2*H + H + h];
    float qx[6], qy[6], mW[6];
    #pragma unroll
    for (int t = 0; t < 6; t++) {
        int w = (half*6 + t)*16 + li;
        float2 qq = Qpn[h*W + w];
        float c0 = cmax[n*2*W + w], c1 = cmax[n*2*W + W + w];
        float lqx = qq.x * LOG2E, lqy = qq.y * LOG2E;
        qx[t] = lqx; qy[t] = lqy;
        mW[t] = fmaxf(fabsf(lqx)*c0 + fabsf(lqy)*c1, fabsf(lqx)*r0 + fabsf(lqy)*r1);
    }

    __syncthreads();

    v4f acc[6] = {};
    float sp[6] = {0.f,0.f,0.f,0.f,0.f,0.f};

    #pragma unroll
    for (int kc = 0; kc < 6; kc++) {
        int j0 = kc*32 + g*8;
        v8s af = *(const v8s*)&Vl[r][li][j0];                 // one ds_read_b128
        const v4f* kp4 = (const v4f*)&Kl[r][j0][0];
        v4f k0 = kp4[0], k1 = kp4[1], k2 = kp4[2], k3 = kp4[3];
        float kxv[8] = {k0[0],k0[2],k1[0],k1[2],k2[0],k2[2],k3[0],k3[2]};
        float kyv[8] = {k0[1],k0[3],k1[1],k1[3],k2[1],k2[3],k3[1],k3[3]};
        #pragma unroll
        for (int t = 0; t < 6; t++) {
            v8s bf;
            float sl = sp[t];
            #pragma unroll
            for (int e = 0; e < 8; e++) {
                float ev = qx[t]*kxv[e] + qy[t]*kyv[e];
                float p = __builtin_amdgcn_exp2f(ev - mW[t]);
                sl += p;
                bf[e] = f2bf(p);
            }
            sp[t] = sl;
            acc[t] = __builtin_amdgcn_mfma_f32_16x16x32_bf16(af, bf, acc[t], 0, 0, 0);
        }
    }

    float gam = gamma_p[0];
    #pragma unroll
    for (int t = 0; t < 6; t++) {
        float s = sp[t];
        s += __shfl_xor(s, 16);
        s += __shfl_xor(s, 32);
        int w = (half*6 + t)*16 + li;
        float st = sC[((long)n*H + h)*W + w] + s;
        float inv = 1.0f / st;
        long po = (long)h*W + w;
        #pragma unroll
        for (int rr = 0; rr < 4; rr++) {
            int c = g*4 + rr;   // D: row = (lane>>4)*4 + reg
            float ac = bf2f(accC[(((long)n*H + h)*16 + c)*W + w]);
            float tot = (acc[t][rr] + ac) * inv;
            out[(long)n*on_s + (long)c*oc_s + po] =
                gam*tot + xres[(long)n*xn_s + (long)c*xc_s + po];
        }
    }
}

extern "C" void kernel_launch(void* const* d_in, const int* in_sizes, int n_in,
                              void* d_out, int out_size, void* d_ws, size_t ws_size,
                              hipStream_t stream) {
    const float* cost = (const float*)d_in[0];   // (1,16,24,96,192)
    const float* q_w  = (const float*)d_in[1];
    const float* q_b  = (const float*)d_in[2];
    const float* k_w  = (const float*)d_in[3];
    const float* k_b  = (const float*)d_in[4];
    const float* v_w  = (const float*)d_in[5];
    const float* v_b  = (const float*)d_in[6];
    const float* gamma= (const float*)d_in[7];
    float* out = (float*)d_out;
    float* ws  = (float*)d_ws;

    float2* Qp = (float2*)(ws + QP_OFF);
    float2* Kp = (float2*)(ws + KP_OFF);
    float4* Vp = (float4*)(ws + VP_OFF);
    float*  cm = ws + CMAX_OFF;
    float*  rm = ws + RMAX_OFF;
    float*  sC = ws + SC_OFF;
    unsigned short* aC = (unsigned short*)(ws + ACC_OFF);

    const int qkv_blocks = (NIMG*PX)/256;   // 1728
    const int col_blocks = NIMG*(H/4);      // 576
    const int row_blocks = NIMG*(H/2);      // 1152

    // ---- pass 1: x = cost_volume [c][n][h][w] (n stride PX, c stride 24*PX) ----
    qkv_kernel<<<qkv_blocks, 256, 0, stream>>>(
        cost, (long)PX, (long)NIMG*PX,
        q_w, q_b, k_w, k_b, v_w, v_b, Qp, Kp, Vp);
    stats_kernel<<<NIMG, 192, 0, stream>>>(Kp, cm, rm);
    col_attn_kernel<<<col_blocks, 384, 0, stream>>>(
        Qp, Kp, (const v4f*)Vp, cm, rm, aC, sC);
    row_attn_kernel<<<row_blocks, 256, 0, stream>>>(
        Qp, Kp, (const v4f*)Vp, cm, rm, aC, sC,
        cost, (long)PX, (long)NIMG*PX,
        out,  (long)PX, (long)NIMG*PX,
        gamma);

    // ---- pass 2: x = d_out (same strides; per-thread same-element RMW is safe) ----
    qkv_kernel<<<qkv_blocks, 256, 0, stream>>>(
        out, (long)PX, (long)NIMG*PX,
        q_w, q_b, k_w, k_b, v_w, v_b, Qp, Kp, Vp);
    stats_kernel<<<NIMG, 192, 0, stream>>>(Kp, cm, rm);
    col_attn_kernel<<<col_blocks, 384, 0, stream>>>(
        Qp, Kp, (const v4f*)Vp, cm, rm, aC, sC);
    row_attn_kernel<<<row_blocks, 256, 0, stream>>>(
        Qp, Kp, (const v4f*)Vp, cm, rm, aC, sC,
        out, (long)PX, (long)NIMG*PX,
        out, (long)PX, (long)NIMG*PX,
        gamma);
}

// Round 16
// 233.991 us; speedup vs baseline: 2.3087x; 1.0937x over previous
//
#include <hip/hip_runtime.h>

#define C 16
#define NIMG 24
#define H 96
#define W 192
#define PX (H*W)            // 18432
#define LOG2E 1.44269504088896f

typedef float v2f  __attribute__((ext_vector_type(2)));
typedef float v4f  __attribute__((ext_vector_type(4)));
typedef short v8s  __attribute__((ext_vector_type(8)));

// workspace float offsets
#define QP_OFF 0                                // float2 [n][px]
#define KP_OFF (NIMG*PX*2)                      // float2 [n][px]
#define VP_OFF (2*NIMG*PX*2)                    // float4 [n][h][c4][w]
#define CMAX_OFF (VP_OFF + NIMG*PX*C)           // 8847360
#define RMAX_OFF (CMAX_OFF + NIMG*2*W)          // 8856576
#define SC_OFF   (RMAX_OFF + NIMG*2*H)          // 8861184  float s_col [n][h][w]
#define ACC_OFF  (SC_OFF + NIMG*PX)             // 9303552  ushort accC [n][h][c][w]

__device__ __forceinline__ short f2bf(float x) {
    union { float f; unsigned u; } v; v.f = x;
    unsigned r = v.u + 0x7fffu + ((v.u >> 16) & 1u);   // RNE
    return (short)(r >> 16);
}
__device__ __forceinline__ float bf2f(unsigned short u) {
    union { unsigned u; float f; } v; v.u = ((unsigned)u) << 16;
    return v.f;
}

__global__ __launch_bounds__(256)
void qkv_kernel(const float* __restrict__ x, long xn_s, long xc_s,
                const float* __restrict__ qw, const float* __restrict__ qb,
                const float* __restrict__ kw, const float* __restrict__ kb,
                const float* __restrict__ vw, const float* __restrict__ vb,
                float2* __restrict__ Qp, float2* __restrict__ Kp,
                float4* __restrict__ Vp)
{
    __shared__ float wq[2*C+2], wk[2*C+2], wv[C*C+C];
    int tid = threadIdx.x;
    if (tid < 2*C) { wq[tid] = qw[tid]; wk[tid] = kw[tid]; }
    if (tid < 2)   { wq[2*C+tid] = qb[tid]; wk[2*C+tid] = kb[tid]; }
    if (tid < C*C) wv[tid] = vw[tid];
    if (tid < C)   wv[C*C+tid] = vb[tid];
    __syncthreads();

    int id = blockIdx.x*256 + tid;        // 0 .. 442367
    int n  = id / PX;
    int p  = id - n*PX;
    int h  = p / W;
    int w  = p - h*W;
    const float* xp = x + (long)n*xn_s + p;

    float xv[C];
    #pragma unroll
    for (int c = 0; c < C; c++) xv[c] = xp[(long)c*xc_s];

    float q0 = wq[2*C], q1 = wq[2*C+1];
    float k0 = wk[2*C], k1 = wk[2*C+1];
    #pragma unroll
    for (int c = 0; c < C; c++) {
        q0 += wq[c]*xv[c];   q1 += wq[C+c]*xv[c];
        k0 += wk[c]*xv[c];   k1 += wk[C+c]*xv[c];
    }
    Qp[id] = make_float2(q0, q1);
    Kp[id] = make_float2(k0, k1);

    float vv[C];
    #pragma unroll
    for (int o = 0; o < C; o++) {
        float a = wv[C*C+o];
        #pragma unroll
        for (int c = 0; c < C; c++) a += wv[o*C+c]*xv[c];
        vv[o] = a;
    }
    #pragma unroll
    for (int c4 = 0; c4 < 4; c4++)
        Vp[(((long)n*H + h)*4 + c4)*W + w] =
            make_float4(vv[c4*4+0], vv[c4*4+1], vv[c4*4+2], vv[c4*4+3]);
}

__global__ __launch_bounds__(192)
void stats_kernel(const float2* __restrict__ Kp,
                  float* __restrict__ cmax, float* __restrict__ rmax)
{
    int n = blockIdx.x;
    int tid = threadIdx.x;
    const float2* Kpn = Kp + n*PX;

    float c0 = 0.f, c1 = 0.f;
    for (int h = 0; h < H; h++) {
        float2 k = Kpn[h*W + tid];
        c0 = fmaxf(c0, fabsf(k.x));
        c1 = fmaxf(c1, fabsf(k.y));
    }
    cmax[n*2*W + tid]     = c0;
    cmax[n*2*W + W + tid] = c1;

    if (tid < H) {
        float r0 = 0.f, r1 = 0.f;
        for (int j = 0; j < W; j++) {
            float2 k = Kpn[tid*W + j];
            r0 = fmaxf(r0, fabsf(k.x));
            r1 = fmaxf(r1, fabsf(k.y));
        }
        rmax[n*2*H + tid]     = r0;
        rmax[n*2*H + H + tid] = r1;
    }
}

// Column (H) attention: 2 rows/thread, 2 rows/block (192 thr, 3 waves),
// 1152 blocks for fine-grained scheduling. 1-deep prefetch pipeline.
// Writes UNNORMALIZED partial acc (bf16) and partial sum s (fp32).
__global__ __launch_bounds__(192)
void col_attn_kernel(const float2* __restrict__ Qp, const float2* __restrict__ Kp,
                     const v4f* __restrict__ Vp,
                     const float* __restrict__ cmax, const float* __restrict__ rmax,
                     unsigned short* __restrict__ accC, float* __restrict__ sC)
{
    const int chunk = (NIMG*(H/2)) / 8;   // 144 ; 1152 % 8 == 0 -> bijective
    int bid = blockIdx.x;
    int swz = (bid & 7)*chunk + (bid >> 3);
    int n   = swz / (H/2);
    int h0  = (swz - n*(H/2)) * 2;
    int w   = threadIdx.x;                // 0..191
    int hr0 = h0;
    int hr1 = h0 + 1;

    const float2* Qpn = Qp + n*PX;
    const float2* Kpn = Kp + n*PX;
    const v4f*    Vpn = Vp + (long)n*PX*4;

    float c0 = cmax[n*2*W + w], c1 = cmax[n*2*W + W + w];
    float qx0, qy0, m0, qx1, qy1, m1;
    {
        float2 qq = Qpn[hr0*W + w];
        qx0 = qq.x * LOG2E;  qy0 = qq.y * LOG2E;
        float r0 = rmax[n*2*H + hr0], r1 = rmax[n*2*H + H + hr0];
        m0 = fmaxf(fabsf(qx0)*c0 + fabsf(qy0)*c1, fabsf(qx0)*r0 + fabsf(qy0)*r1);
    }
    {
        float2 qq = Qpn[hr1*W + w];
        qx1 = qq.x * LOG2E;  qy1 = qq.y * LOG2E;
        float r0 = rmax[n*2*H + hr1], r1 = rmax[n*2*H + H + hr1];
        m1 = fmaxf(fabsf(qx1)*c0 + fabsf(qy1)*c1, fabsf(qx1)*r0 + fabsf(qy1)*r1);
    }

    v4f acc0[4] = {}, acc1[4] = {};
    float s0 = 0.f, s1 = 0.f;

    const float2* kp = Kpn + w;
    const v4f*    vp = Vpn + w;

    // prologue: load j=0
    float2 kc = *kp;
    v4f b0 = vp[0*W], b1 = vp[1*W], b2 = vp[2*W], b3 = vp[3*W];

#define COL_STEP(J, KK, A0, A1, A2, A3) do {                                   \
        float e0 = qx0*(KK).x + qy0*(KK).y;                                    \
        float p0 = __builtin_amdgcn_exp2f(e0 - m0);                            \
        p0 = ((J) == hr0) ? 0.0f : p0;                                         \
        float e1 = qx1*(KK).x + qy1*(KK).y;                                    \
        float p1 = __builtin_amdgcn_exp2f(e1 - m1);                            \
        p1 = ((J) == hr1) ? 0.0f : p1;                                         \
        s0 += p0;  s1 += p1;                                                   \
        acc0[0] += (A0)*p0; acc0[1] += (A1)*p0; acc0[2] += (A2)*p0; acc0[3] += (A3)*p0; \
        acc1[0] += (A0)*p1; acc1[1] += (A1)*p1; acc1[2] += (A2)*p1; acc1[3] += (A3)*p1; \
    } while (0)

    for (int j = 0; j < H-1; j++) {
        // issue next-j loads first (5 loads in flight during compute)
        float2 kn = kp[W];
        v4f n0 = vp[4*W], n1 = vp[5*W], n2 = vp[6*W], n3 = vp[7*W];
        COL_STEP(j, kc, b0, b1, b2, b3);
        kc = kn; b0 = n0; b1 = n1; b2 = n2; b3 = n3;
        kp += W; vp += 4*W;
    }
    COL_STEP(H-1, kc, b0, b1, b2, b3);
#undef COL_STEP

    sC[((long)n*H + hr0)*W + w] = s0;
    sC[((long)n*H + hr1)*W + w] = s1;
    #pragma unroll
    for (int c = 0; c < C; c++)
        accC[(((long)n*H + hr0)*16 + c)*W + w] = (unsigned short)f2bf(acc0[c>>2][c&3]);
    #pragma unroll
    for (int c = 0; c < C; c++)
        accC[(((long)n*H + hr1)*16 + c)*W + w] = (unsigned short)f2bf(acc1[c>>2][c&3]);
}

// Row (W) attention as MFMA. Block = 2 rows; stages V (bf16) + K (fp32) in LDS.
// Wave (r, half) computes 6 D[16c x 16w] tiles via 6 k-chunks of 16x16x32 bf16 MFMA.
__global__ __launch_bounds__(256)
void row_attn_kernel(const float2* __restrict__ Qp, const float2* __restrict__ Kp,
                     const v4f* __restrict__ Vp,
                     const float* __restrict__ cmax, const float* __restrict__ rmax,
                     const unsigned short* __restrict__ accC, const float* __restrict__ sC,
                     const float* __restrict__ xres, long xn_s, long xc_s,
                     float* __restrict__ out, long on_s, long oc_s,
                     const float* __restrict__ gamma_p)
{
    __shared__ __align__(16) unsigned short Vl[2][16][200];  // bf16, pad 192->200
    __shared__ __align__(16) float          Kl[2][192][2];   // fp32 kx,ky

    const int chunk = (NIMG*(H/2)) / 8;   // 144
    int bid = blockIdx.x;
    int swz = (bid & 7)*chunk + (bid >> 3);
    int n   = swz / (H/2);
    int h0  = (swz - n*(H/2)) * 2;
    int tid = threadIdx.x;

    const float2* Qpn = Qp + n*PX;
    const float2* Kpn = Kp + n*PX;
    const v4f*    Vpn = Vp + (long)n*PX*4;

    // ---- stage: V 2 rows x 4 c4 x 192 w = 1536 float4s, 6 per thread ----
    #pragma unroll
    for (int i = 0; i < 6; i++) {
        int idx = i*256 + tid;            // 0..1535
        int rr  = idx / 768;              // 768 = 4*192
        int rem = idx - rr*768;
        int c4  = rem / 192;
        int w2  = rem - c4*192;
        v4f v = Vpn[((long)(h0+rr)*4 + c4)*W + w2];
        Vl[rr][c4*4+0][w2] = (unsigned short)f2bf(v[0]);
        Vl[rr][c4*4+1][w2] = (unsigned short)f2bf(v[1]);
        Vl[rr][c4*4+2][w2] = (unsigned short)f2bf(v[2]);
        Vl[rr][c4*4+3][w2] = (unsigned short)f2bf(v[3]);
    }
    // K staging: 256-thread block -> tid<192 threads each stage BOTH rows
    if (tid < 192) {
        float2 ka = Kpn[(h0+0)*W + tid];
        float2 kb = Kpn[(h0+1)*W + tid];
        Kl[0][tid][0] = ka.x;  Kl[0][tid][1] = ka.y;
        Kl[1][tid][0] = kb.x;  Kl[1][tid][1] = kb.y;
    }

    int wv   = tid >> 6;        // 0..3
    int r    = wv >> 1;
    int half = wv & 1;
    int lane = tid & 63;
    int li   = lane & 15;
    int g    = lane >> 4;
    int h    = h0 + r;

    float r0 = rmax[n*2*H + h], r1 = rmax[n*2*H + H + h];
    float qx[6], qy[6], mW[6];
    #pragma unroll
    for (int t = 0; t < 6; t++) {
        int w = (half*6 + t)*16 + li;
        float2 qq = Qpn[h*W + w];
        float c0 = cmax[n*2*W + w], c1 = cmax[n*2*W + W + w];
        float lqx = qq.x * LOG2E, lqy = qq.y * LOG2E;
        qx[t] = lqx; qy[t] = lqy;
        mW[t] = fmaxf(fabsf(lqx)*c0 + fabsf(lqy)*c1, fabsf(lqx)*r0 + fabsf(lqy)*r1);
    }

    __syncthreads();

    v4f acc[6] = {};
    float sp[6] = {0.f,0.f,0.f,0.f,0.f,0.f};

    #pragma unroll
    for (int kc = 0; kc < 6; kc++) {
        int j0 = kc*32 + g*8;
        v8s af = *(const v8s*)&Vl[r][li][j0];                 // one ds_read_b128
        const v4f* kp4 = (const v4f*)&Kl[r][j0][0];
        v4f k0 = kp4[0], k1 = kp4[1], k2 = kp4[2], k3 = kp4[3];
        float kxv[8] = {k0[0],k0[2],k1[0],k1[2],k2[0],k2[2],k3[0],k3[2]};
        float kyv[8] = {k0[1],k0[3],k1[1],k1[3],k2[1],k2[3],k3[1],k3[3]};
        #pragma unroll
        for (int t = 0; t < 6; t++) {
            v8s bf;
            float sl = sp[t];
            #pragma unroll
            for (int e = 0; e < 8; e++) {
                float ev = qx[t]*kxv[e] + qy[t]*kyv[e];
                float p = __builtin_amdgcn_exp2f(ev - mW[t]);
                sl += p;
                bf[e] = f2bf(p);
            }
            sp[t] = sl;
            acc[t] = __builtin_amdgcn_mfma_f32_16x16x32_bf16(af, bf, acc[t], 0, 0, 0);
        }
    }

    float gam = gamma_p[0];
    #pragma unroll
    for (int t = 0; t < 6; t++) {
        float s = sp[t];
        s += __shfl_xor(s, 16);
        s += __shfl_xor(s, 32);
        int w = (half*6 + t)*16 + li;
        float st = sC[((long)n*H + h)*W + w] + s;
        float inv = 1.0f / st;
        long po = (long)h*W + w;
        #pragma unroll
        for (int rr = 0; rr < 4; rr++) {
            int c = g*4 + rr;   // D: row = (lane>>4)*4 + reg
            float ac = bf2f(accC[(((long)n*H + h)*16 + c)*W + w]);
            float tot = (acc[t][rr] + ac) * inv;
            out[(long)n*on_s + (long)c*oc_s + po] =
                gam*tot + xres[(long)n*xn_s + (long)c*xc_s + po];
        }
    }
}

extern "C" void kernel_launch(void* const* d_in, const int* in_sizes, int n_in,
                              void* d_out, int out_size, void* d_ws, size_t ws_size,
                              hipStream_t stream) {
    const float* cost = (const float*)d_in[0];   // (1,16,24,96,192)
    const float* q_w  = (const float*)d_in[1];
    const float* q_b  = (const float*)d_in[2];
    const float* k_w  = (const float*)d_in[3];
    const float* k_b  = (const float*)d_in[4];
    const float* v_w  = (const float*)d_in[5];
    const float* v_b  = (const float*)d_in[6];
    const float* gamma= (const float*)d_in[7];
    float* out = (float*)d_out;
    float* ws  = (float*)d_ws;

    float2* Qp = (float2*)(ws + QP_OFF);
    float2* Kp = (float2*)(ws + KP_OFF);
    float4* Vp = (float4*)(ws + VP_OFF);
    float*  cm = ws + CMAX_OFF;
    float*  rm = ws + RMAX_OFF;
    float*  sC = ws + SC_OFF;
    unsigned short* aC = (unsigned short*)(ws + ACC_OFF);

    const int qkv_blocks = (NIMG*PX)/256;   // 1728
    const int col_blocks = NIMG*(H/2);      // 1152
    const int row_blocks = NIMG*(H/2);      // 1152

    // ---- pass 1: x = cost_volume [c][n][h][w] (n stride PX, c stride 24*PX) ----
    qkv_kernel<<<qkv_blocks, 256, 0, stream>>>(
        cost, (long)PX, (long)NIMG*PX,
        q_w, q_b, k_w, k_b, v_w, v_b, Qp, Kp, Vp);
    stats_kernel<<<NIMG, 192, 0, stream>>>(Kp, cm, rm);
    col_attn_kernel<<<col_blocks, 192, 0, stream>>>(
        Qp, Kp, (const v4f*)Vp, cm, rm, aC, sC);
    row_attn_kernel<<<row_blocks, 256, 0, stream>>>(
        Qp, Kp, (const v4f*)Vp, cm, rm, aC, sC,
        cost, (long)PX, (long)NIMG*PX,
        out,  (long)PX, (long)NIMG*PX,
        gamma);

    // ---- pass 2: x = d_out (same strides; per-thread same-element RMW is safe) ----
    qkv_kernel<<<qkv_blocks, 256, 0, stream>>>(
        out, (long)PX, (long)NIMG*PX,
        q_w, q_b, k_w, k_b, v_w, v_b, Qp, Kp, Vp);
    stats_kernel<<<NIMG, 192, 0, stream>>>(Kp, cm, rm);
    col_attn_kernel<<<col_blocks, 192, 0, stream>>>(
        Qp, Kp, (const v4f*)Vp, cm, rm, aC, sC);
    row_attn_kernel<<<row_blocks, 256, 0, stream>>>(
        Qp, Kp, (const v4f*)Vp, cm, rm, aC, sC,
        out, (long)PX, (long)NIMG*PX,
        out, (long)PX, (long)NIMG*PX,
        gamma);
}

// Round 17
// 233.779 us; speedup vs baseline: 2.3108x; 1.0009x over previous
//
#include <hip/hip_runtime.h>

#define C 16
#define NIMG 24
#define H 96
#define W 192
#define PX (H*W)            // 18432
#define LOG2E 1.44269504088896f

typedef float v2f  __attribute__((ext_vector_type(2)));
typedef float v4f  __attribute__((ext_vector_type(4)));
typedef short v8s  __attribute__((ext_vector_type(8)));

// workspace float offsets
#define QP_OFF 0                                // float2 [n][px]
#define KP_OFF (NIMG*PX*2)                      // float2 [n][px]
#define VP_OFF (2*NIMG*PX*2)                    // float4 [n][h][c4][w]
#define CMAX_OFF (VP_OFF + NIMG*PX*C)           // 8847360
#define RMAX_OFF (CMAX_OFF + NIMG*2*W)          // 8856576

__device__ __forceinline__ short f2bf(float x) {
    union { float f; unsigned u; } v; v.f = x;
    unsigned r = v.u + 0x7fffu + ((v.u >> 16) & 1u);   // RNE
    return (short)(r >> 16);
}
__device__ __forceinline__ float bf2f(unsigned short u) {
    union { unsigned u; float f; } v; v.u = ((unsigned)u) << 16;
    return v.f;
}

__global__ __launch_bounds__(256)
void qkv_kernel(const float* __restrict__ x, long xn_s, long xc_s,
                const float* __restrict__ qw, const float* __restrict__ qb,
                const float* __restrict__ kw, const float* __restrict__ kb,
                const float* __restrict__ vw, const float* __restrict__ vb,
                float2* __restrict__ Qp, float2* __restrict__ Kp,
                float4* __restrict__ Vp)
{
    __shared__ float wq[2*C+2], wk[2*C+2], wv[C*C+C];
    int tid = threadIdx.x;
    if (tid < 2*C) { wq[tid] = qw[tid]; wk[tid] = kw[tid]; }
    if (tid < 2)   { wq[2*C+tid] = qb[tid]; wk[2*C+tid] = kb[tid]; }
    if (tid < C*C) wv[tid] = vw[tid];
    if (tid < C)   wv[C*C+tid] = vb[tid];
    __syncthreads();

    int id = blockIdx.x*256 + tid;        // 0 .. 442367
    int n  = id / PX;
    int p  = id - n*PX;
    int h  = p / W;
    int w  = p - h*W;
    const float* xp = x + (long)n*xn_s + p;

    float xv[C];
    #pragma unroll
    for (int c = 0; c < C; c++) xv[c] = xp[(long)c*xc_s];

    float q0 = wq[2*C], q1 = wq[2*C+1];
    float k0 = wk[2*C], k1 = wk[2*C+1];
    #pragma unroll
    for (int c = 0; c < C; c++) {
        q0 += wq[c]*xv[c];   q1 += wq[C+c]*xv[c];
        k0 += wk[c]*xv[c];   k1 += wk[C+c]*xv[c];
    }
    Qp[id] = make_float2(q0, q1);
    Kp[id] = make_float2(k0, k1);

    float vv[C];
    #pragma unroll
    for (int o = 0; o < C; o++) {
        float a = wv[C*C+o];
        #pragma unroll
        for (int c = 0; c < C; c++) a += wv[o*C+c]*xv[c];
        vv[o] = a;
    }
    #pragma unroll
    for (int c4 = 0; c4 < 4; c4++)
        Vp[(((long)n*H + h)*4 + c4)*W + w] =
            make_float4(vv[c4*4+0], vv[c4*4+1], vv[c4*4+2], vv[c4*4+3]);
}

__global__ __launch_bounds__(192)
void stats_kernel(const float2* __restrict__ Kp,
                  float* __restrict__ cmax, float* __restrict__ rmax)
{
    int n = blockIdx.x;
    int tid = threadIdx.x;
    const float2* Kpn = Kp + n*PX;

    float c0 = 0.f, c1 = 0.f;
    for (int h = 0; h < H; h++) {
        float2 k = Kpn[h*W + tid];
        c0 = fmaxf(c0, fabsf(k.x));
        c1 = fmaxf(c1, fabsf(k.y));
    }
    cmax[n*2*W + tid]     = c0;
    cmax[n*2*W + W + tid] = c1;

    if (tid < H) {
        float r0 = 0.f, r1 = 0.f;
        for (int j = 0; j < W; j++) {
            float2 k = Kpn[tid*W + j];
            r0 = fmaxf(r0, fabsf(k.x));
            r1 = fmaxf(r1, fabsf(k.y));
        }
        rmax[n*2*H + tid]     = r0;
        rmax[n*2*H + H + tid] = r1;
    }
}

// Fused attention per (n, row pair): col phase (VALU, 2-deep prefetch) writes
// partials to LDS; row phase (MFMA) merges, normalizes, stores. One barrier.
__global__ __launch_bounds__(192)
void fused_attn_kernel(const float2* __restrict__ Qp, const float2* __restrict__ Kp,
                       const v4f* __restrict__ Vp,
                       const float* __restrict__ cmax, const float* __restrict__ rmax,
                       const float* __restrict__ xres, long xn_s, long xc_s,
                       float* __restrict__ out, long on_s, long oc_s,
                       const float* __restrict__ gamma_p)
{
    __shared__ __align__(16) unsigned short Vl[2][16][200];  // bf16 V rows (pad->200)
    __shared__ __align__(16) float          Kl[2][192][2];   // fp32 kx,ky
    __shared__ unsigned short CA[2][16][192];                // col partial acc (bf16)
    __shared__ float          CS[2][192];                    // col partial sum

    const int chunk = (NIMG*(H/2)) / 8;   // 144 ; 1152 % 8 == 0 -> bijective
    int bid = blockIdx.x;
    int swz = (bid & 7)*chunk + (bid >> 3);
    int n   = swz / (H/2);
    int h0  = (swz - n*(H/2)) * 2;
    int tid = threadIdx.x;
    int w   = tid;                        // 0..191 (col phase lane = w)
    int hr0 = h0;
    int hr1 = h0 + 1;

    const float2* Qpn = Qp + n*PX;
    const float2* Kpn = Kp + n*PX;
    const v4f*    Vpn = Vp + (long)n*PX*4;

    // ---- stage V (bf16) + K (fp32) rows into LDS (for row phase) ----
    #pragma unroll
    for (int i = 0; i < 8; i++) {
        int idx = i*192 + tid;            // 0..1535
        int rr  = idx / 768;
        int rem = idx - rr*768;
        int c4  = rem / 192;
        int w2  = rem - c4*192;
        v4f v = Vpn[((long)(h0+rr)*4 + c4)*W + w2];
        Vl[rr][c4*4+0][w2] = (unsigned short)f2bf(v[0]);
        Vl[rr][c4*4+1][w2] = (unsigned short)f2bf(v[1]);
        Vl[rr][c4*4+2][w2] = (unsigned short)f2bf(v[2]);
        Vl[rr][c4*4+3][w2] = (unsigned short)f2bf(v[3]);
    }
    {
        float2 ka = Kpn[(h0+0)*W + tid];
        float2 kb = Kpn[(h0+1)*W + tid];
        Kl[0][tid][0] = ka.x;  Kl[0][tid][1] = ka.y;
        Kl[1][tid][0] = kb.x;  Kl[1][tid][1] = kb.y;
    }

    // ---- col phase: 2 rows/thread over 96 column entries, 2-deep prefetch ----
    float c0 = cmax[n*2*W + w], c1 = cmax[n*2*W + W + w];
    float qx0, qy0, m0, qx1, qy1, m1;
    {
        float2 qq = Qpn[hr0*W + w];
        qx0 = qq.x * LOG2E;  qy0 = qq.y * LOG2E;
        float r0 = rmax[n*2*H + hr0], r1 = rmax[n*2*H + H + hr0];
        m0 = fmaxf(fabsf(qx0)*c0 + fabsf(qy0)*c1, fabsf(qx0)*r0 + fabsf(qy0)*r1);
    }
    {
        float2 qq = Qpn[hr1*W + w];
        qx1 = qq.x * LOG2E;  qy1 = qq.y * LOG2E;
        float r0 = rmax[n*2*H + hr1], r1 = rmax[n*2*H + H + hr1];
        m1 = fmaxf(fabsf(qx1)*c0 + fabsf(qy1)*c1, fabsf(qx1)*r0 + fabsf(qy1)*r1);
    }

    v4f acc0[4] = {}, acc1[4] = {};
    float s0 = 0.f, s1 = 0.f;

    const float2* kp = Kpn + w;
    const v4f*    vp = Vpn + w;

    float2 kA = kp[0];
    v4f A0 = vp[0*W], A1 = vp[1*W], A2 = vp[2*W], A3 = vp[3*W];
    float2 kB = kp[W];
    v4f B0 = vp[4*W], B1 = vp[5*W], B2 = vp[6*W], B3 = vp[7*W];

#define COL_STEP(J, KK, X0, X1, X2, X3) do {                                   \
        float e0 = qx0*(KK).x + qy0*(KK).y;                                    \
        float p0 = __builtin_amdgcn_exp2f(e0 - m0);                            \
        p0 = ((J) == hr0) ? 0.0f : p0;                                         \
        float e1 = qx1*(KK).x + qy1*(KK).y;                                    \
        float p1 = __builtin_amdgcn_exp2f(e1 - m1);                            \
        p1 = ((J) == hr1) ? 0.0f : p1;                                         \
        s0 += p0;  s1 += p1;                                                   \
        acc0[0] += (X0)*p0; acc0[1] += (X1)*p0; acc0[2] += (X2)*p0; acc0[3] += (X3)*p0; \
        acc1[0] += (X0)*p1; acc1[1] += (X1)*p1; acc1[2] += (X2)*p1; acc1[3] += (X3)*p1; \
    } while (0)

    for (int j = 0; j < H-2; j++) {
        float2 kC = kp[2*W];
        v4f C0 = vp[8*W], C1 = vp[9*W], C2 = vp[10*W], C3 = vp[11*W];
        COL_STEP(j, kA, A0, A1, A2, A3);
        kA = kB; A0 = B0; A1 = B1; A2 = B2; A3 = B3;
        kB = kC; B0 = C0; B1 = C1; B2 = C2; B3 = C3;
        kp += W; vp += 4*W;
    }
    COL_STEP(H-2, kA, A0, A1, A2, A3);
    COL_STEP(H-1, kB, B0, B1, B2, B3);
#undef COL_STEP

    // publish col partials to LDS
    #pragma unroll
    for (int c = 0; c < C; c++) {
        CA[0][c][w] = (unsigned short)f2bf(acc0[c>>2][c&3]);
        CA[1][c][w] = (unsigned short)f2bf(acc1[c>>2][c&3]);
    }
    CS[0][w] = s0;
    CS[1][w] = s1;

    __syncthreads();

    // ---- row phase: 24 (r, wtile) tiles over 3 waves, 6 MFMA k-chunks each ----
    int wvid = tid >> 6;        // 0..2
    int lane = tid & 63;
    int li   = lane & 15;
    int g    = lane >> 4;
    float gam = gamma_p[0];

    for (int i = 0; i < 8; i++) {
        int idx = wvid*8 + i;             // 0..23
        int r   = idx / 12;
        int wt  = idx - r*12;
        int h   = h0 + r;
        int w2  = wt*16 + li;

        float2 qq = Qpn[h*W + w2];
        float cc0 = cmax[n*2*W + w2], cc1 = cmax[n*2*W + W + w2];
        float rr0 = rmax[n*2*H + h],  rr1 = rmax[n*2*H + H + h];
        float qx = qq.x * LOG2E, qy = qq.y * LOG2E;
        float m  = fmaxf(fabsf(qx)*cc0 + fabsf(qy)*cc1, fabsf(qx)*rr0 + fabsf(qy)*rr1);

        v4f acc = {};
        float sp = 0.f;
        #pragma unroll
        for (int kc = 0; kc < 6; kc++) {
            int j0 = kc*32 + g*8;
            v8s af = *(const v8s*)&Vl[r][li][j0];
            const v4f* kp4 = (const v4f*)&Kl[r][j0][0];
            v4f k0 = kp4[0], k1 = kp4[1], k2 = kp4[2], k3 = kp4[3];
            float kxv[8] = {k0[0],k0[2],k1[0],k1[2],k2[0],k2[2],k3[0],k3[2]};
            float kyv[8] = {k0[1],k0[3],k1[1],k1[3],k2[1],k2[3],k3[1],k3[3]};
            v8s bf;
            #pragma unroll
            for (int e = 0; e < 8; e++) {
                float ev = qx*kxv[e] + qy*kyv[e];
                float p = __builtin_amdgcn_exp2f(ev - m);
                sp += p;
                bf[e] = f2bf(p);
            }
            acc = __builtin_amdgcn_mfma_f32_16x16x32_bf16(af, bf, acc, 0, 0, 0);
        }
        sp += __shfl_xor(sp, 16);
        sp += __shfl_xor(sp, 32);

        float st = CS[r][w2] + sp;
        float inv = 1.0f / st;
        long po = (long)h*W + w2;
        #pragma unroll
        for (int rr = 0; rr < 4; rr++) {
            int c = g*4 + rr;   // D: row = (lane>>4)*4 + reg
            float ac = bf2f(CA[r][c][w2]);
            float tot = (acc[rr] + ac) * inv;
            out[(long)n*on_s + (long)c*oc_s + po] =
                gam*tot + xres[(long)n*xn_s + (long)c*xc_s + po];
        }
    }
}

extern "C" void kernel_launch(void* const* d_in, const int* in_sizes, int n_in,
                              void* d_out, int out_size, void* d_ws, size_t ws_size,
                              hipStream_t stream) {
    const float* cost = (const float*)d_in[0];   // (1,16,24,96,192)
    const float* q_w  = (const float*)d_in[1];
    const float* q_b  = (const float*)d_in[2];
    const float* k_w  = (const float*)d_in[3];
    const float* k_b  = (const float*)d_in[4];
    const float* v_w  = (const float*)d_in[5];
    const float* v_b  = (const float*)d_in[6];
    const float* gamma= (const float*)d_in[7];
    float* out = (float*)d_out;
    float* ws  = (float*)d_ws;

    float2* Qp = (float2*)(ws + QP_OFF);
    float2* Kp = (float2*)(ws + KP_OFF);
    float4* Vp = (float4*)(ws + VP_OFF);
    float*  cm = ws + CMAX_OFF;
    float*  rm = ws + RMAX_OFF;

    const int qkv_blocks  = (NIMG*PX)/256;   // 1728
    const int attn_blocks = NIMG*(H/2);      // 1152

    // ---- pass 1: x = cost_volume [c][n][h][w] (n stride PX, c stride 24*PX) ----
    qkv_kernel<<<qkv_blocks, 256, 0, stream>>>(
        cost, (long)PX, (long)NIMG*PX,
        q_w, q_b, k_w, k_b, v_w, v_b, Qp, Kp, Vp);
    stats_kernel<<<NIMG, 192, 0, stream>>>(Kp, cm, rm);
    fused_attn_kernel<<<attn_blocks, 192, 0, stream>>>(
        Qp, Kp, (const v4f*)Vp, cm, rm,
        cost, (long)PX, (long)NIMG*PX,
        out,  (long)PX, (long)NIMG*PX,
        gamma);

    // ---- pass 2: x = d_out (same strides; per-thread same-element RMW is safe) ----
    qkv_kernel<<<qkv_blocks, 256, 0, stream>>>(
        out, (long)PX, (long)NIMG*PX,
        q_w, q_b, k_w, k_b, v_w, v_b, Qp, Kp, Vp);
    stats_kernel<<<NIMG, 192, 0, stream>>>(Kp, cm, rm);
    fused_attn_kernel<<<attn_blocks, 192, 0, stream>>>(
        Qp, Kp, (const v4f*)Vp, cm, rm,
        out, (long)PX, (long)NIMG*PX,
        out, (long)PX, (long)NIMG*PX,
        gamma);
}

// Round 18
// 166.262 us; speedup vs baseline: 3.2491x; 1.4061x over previous
//
#include <hip/hip_runtime.h>

#define C 16
#define NIMG 24
#define H 96
#define W 192
#define PX (H*W)            // 18432
#define LOG2E 1.44269504088896f

typedef float v2f  __attribute__((ext_vector_type(2)));
typedef float v4f  __attribute__((ext_vector_type(4)));
typedef short v8s  __attribute__((ext_vector_type(8)));

// workspace float offsets
#define QP_OFF 0                                // float2 [n][px]
#define KP_OFF (NIMG*PX*2)                      // float2 [n][px]
#define VP_OFF (2*NIMG*PX*2)                    // float4 [n][h][c4][w]
#define CMAX_OFF (VP_OFF + NIMG*PX*C)           // 8847360
#define RMAX_OFF (CMAX_OFF + NIMG*2*W)          // 8856576
#define SC_OFF   (RMAX_OFF + NIMG*2*H)          // 8861184  float s_col [n][h][w]
#define ACC_OFF  (SC_OFF + NIMG*PX)             // 9303552  ushort accC [n][h][w][c]

__device__ __forceinline__ short f2bf(float x) {
    union { float f; unsigned u; } v; v.f = x;
    unsigned r = v.u + 0x7fffu + ((v.u >> 16) & 1u);   // RNE
    return (short)(r >> 16);
}
__device__ __forceinline__ float bf2f(unsigned short u) {
    union { unsigned u; float f; } v; v.u = ((unsigned)u) << 16;
    return v.f;
}

__global__ __launch_bounds__(256)
void qkv_kernel(const float* __restrict__ x, long xn_s, long xc_s,
                const float* __restrict__ qw, const float* __restrict__ qb,
                const float* __restrict__ kw, const float* __restrict__ kb,
                const float* __restrict__ vw, const float* __restrict__ vb,
                float2* __restrict__ Qp, float2* __restrict__ Kp,
                float4* __restrict__ Vp)
{
    __shared__ float wq[2*C+2], wk[2*C+2], wv[C*C+C];
    int tid = threadIdx.x;
    if (tid < 2*C) { wq[tid] = qw[tid]; wk[tid] = kw[tid]; }
    if (tid < 2)   { wq[2*C+tid] = qb[tid]; wk[2*C+tid] = kb[tid]; }
    if (tid < C*C) wv[tid] = vw[tid];
    if (tid < C)   wv[C*C+tid] = vb[tid];
    __syncthreads();

    int id = blockIdx.x*256 + tid;        // 0 .. 442367
    int n  = id / PX;
    int p  = id - n*PX;
    int h  = p / W;
    int w  = p - h*W;
    const float* xp = x + (long)n*xn_s + p;

    float xv[C];
    #pragma unroll
    for (int c = 0; c < C; c++) xv[c] = xp[(long)c*xc_s];

    float q0 = wq[2*C], q1 = wq[2*C+1];
    float k0 = wk[2*C], k1 = wk[2*C+1];
    #pragma unroll
    for (int c = 0; c < C; c++) {
        q0 += wq[c]*xv[c];   q1 += wq[C+c]*xv[c];
        k0 += wk[c]*xv[c];   k1 += wk[C+c]*xv[c];
    }
    Qp[id] = make_float2(q0, q1);
    Kp[id] = make_float2(k0, k1);

    float vv[C];
    #pragma unroll
    for (int o = 0; o < C; o++) {
        float a = wv[C*C+o];
        #pragma unroll
        for (int c = 0; c < C; c++) a += wv[o*C+c]*xv[c];
        vv[o] = a;
    }
    #pragma unroll
    for (int c4 = 0; c4 < 4; c4++)
        Vp[(((long)n*H + h)*4 + c4)*W + w] =
            make_float4(vv[c4*4+0], vv[c4*4+1], vv[c4*4+2], vv[c4*4+3]);
}

__global__ __launch_bounds__(192)
void stats_kernel(const float2* __restrict__ Kp,
                  float* __restrict__ cmax, float* __restrict__ rmax)
{
    int n = blockIdx.x;
    int tid = threadIdx.x;
    const float2* Kpn = Kp + n*PX;

    float c0 = 0.f, c1 = 0.f;
    for (int h = 0; h < H; h++) {
        float2 k = Kpn[h*W + tid];
        c0 = fmaxf(c0, fabsf(k.x));
        c1 = fmaxf(c1, fabsf(k.y));
    }
    cmax[n*2*W + tid]     = c0;
    cmax[n*2*W + W + tid] = c1;

    if (tid < H) {
        float r0 = 0.f, r1 = 0.f;
        for (int j = 0; j < W; j++) {
            float2 k = Kpn[tid*W + j];
            r0 = fmaxf(r0, fabsf(k.x));
            r1 = fmaxf(r1, fabsf(k.y));
        }
        rmax[n*2*H + tid]     = r0;
        rmax[n*2*H + H + tid] = r1;
    }
}

// Column (H) attention as MFMA. Block = (n, 4 columns), 256 thr = 4 waves,
// wave wv owns column wl=wv. Per column: out[16c x 96h] = V^T @ P via
// 6 h-tiles x 3 k-chunks of 16x16x32 bf16 MFMA. A=P (built in-register),
// B=V^T (one ds_read_b128) — same slot->j convention both operands.
// Writes UNNORMALIZED acc (bf16, [n][h][w][c]) and sum s (fp32, [n][h][w]).
#define VT_WS 1672   // per-w Vt stride in ushorts: 16*104 + 8 pad
__global__ __launch_bounds__(256)
void col_attn_kernel(const float2* __restrict__ Qp, const float2* __restrict__ Kp,
                     const v4f* __restrict__ Vp,
                     const float* __restrict__ cmax, const float* __restrict__ rmax,
                     unsigned short* __restrict__ accC, float* __restrict__ sC)
{
    __shared__ unsigned short Vt[4*VT_WS];      // V^T: [wl][c][j] bf16, j-pad 104
    __shared__ unsigned short Ks[4*2*96];       // K:   [wl][ch][j] bf16
    __shared__ float2         Qs[4*96];         // q (log2-scaled): [wl][h]
    __shared__ float          Ms[4*96];         // shift bound m:   [wl][h]

    const int chunk = (NIMG*48) / 8;            // 144 ; 1152 % 8 == 0
    int bid = blockIdx.x;
    int swz = (bid & 7)*chunk + (bid >> 3);
    int n   = swz / 48;
    int wg  = swz - n*48;
    int w0  = wg*4;
    int tid = threadIdx.x;

    const float2* Qpn = Qp + n*PX;
    const float2* Kpn = Kp + n*PX;
    const v4f*    Vpn = Vp + (long)n*PX*4;

    // ---- stage V^T (1536 v4f, 6/thread) ----
    #pragma unroll
    for (int i = 0; i < 6; i++) {
        int idx = i*256 + tid;        // 0..1535
        int wl  = idx & 3;
        int c4  = (idx >> 2) & 3;
        int j   = idx >> 4;           // 0..95
        v4f v = Vpn[((long)j*4 + c4)*W + w0 + wl];
        int b = wl*VT_WS + (c4*4)*104 + j;
        Vt[b        ] = (unsigned short)f2bf(v[0]);
        Vt[b + 104  ] = (unsigned short)f2bf(v[1]);
        Vt[b + 208  ] = (unsigned short)f2bf(v[2]);
        Vt[b + 312  ] = (unsigned short)f2bf(v[3]);
    }
    // ---- stage K (384 float2) ----
    #pragma unroll
    for (int i = 0; i < 2; i++) {
        int idx = i*256 + tid;
        if (idx < 384) {
            int wl = idx & 3;
            int j  = idx >> 2;
            float2 kk = Kpn[j*W + w0 + wl];
            Ks[wl*192 + j]      = (unsigned short)f2bf(kk.x);
            Ks[wl*192 + 96 + j] = (unsigned short)f2bf(kk.y);
        }
    }
    // ---- stage Q (log2 domain) + m bound (384 items) ----
    #pragma unroll
    for (int i = 0; i < 2; i++) {
        int idx = i*256 + tid;
        if (idx < 384) {
            int wl = idx & 3;
            int h  = idx >> 2;
            int w  = w0 + wl;
            float2 qq = Qpn[h*W + w];
            float qx = qq.x * LOG2E, qy = qq.y * LOG2E;
            float c0 = cmax[n*2*W + w], c1 = cmax[n*2*W + W + w];
            float r0 = rmax[n*2*H + h], r1 = rmax[n*2*H + H + h];
            float ax = fabsf(qx), ay = fabsf(qy);
            Qs[wl*96 + h] = make_float2(qx, qy);
            Ms[wl*96 + h] = fmaxf(ax*c0 + ay*c1, ax*r0 + ay*r1);
        }
    }
    __syncthreads();

    int wl   = tid >> 6;        // wave id 0..3 = column
    int lane = tid & 63;
    int li   = lane & 15;
    int g    = lane >> 4;
    int w    = w0 + wl;
    unsigned short* accCn = accC + (long)n*PX*16;

    #pragma unroll
    for (int ht = 0; ht < 6; ht++) {
        int hglob = ht*16 + li;                 // A' row (h) for this lane
        float2 q = Qs[wl*96 + hglob];
        float  m = Ms[wl*96 + hglob];

        v4f acc = {};
        float sp = 0.f;
        #pragma unroll
        for (int kc = 0; kc < 3; kc++) {
            int j0 = kc*32 + g*8;
            v8s bv = *(const v8s*)&Vt[wl*VT_WS + li*104 + j0];   // B' = V^T (c=li)
            v8s kxv = *(const v8s*)&Ks[wl*192 + j0];
            v8s kyv = *(const v8s*)&Ks[wl*192 + 96 + j0];
            v8s af;                                              // A' = P (h=li)
            #pragma unroll
            for (int e = 0; e < 8; e++) {
                float e2 = bf2f((unsigned short)kxv[e])*q.x
                         + bf2f((unsigned short)kyv[e])*q.y - m;
                float p = __builtin_amdgcn_exp2f(e2);
                p = (j0 + e == hglob) ? 0.0f : p;               // diag mask
                sp += p;
                af[e] = f2bf(p);
            }
            acc = __builtin_amdgcn_mfma_f32_16x16x32_bf16(af, bv, acc, 0, 0, 0);
        }
        // s[h=hglob]: reduce partial sums across g groups
        sp += __shfl_xor(sp, 16);
        sp += __shfl_xor(sp, 32);
        if (lane < 16)
            sC[((long)n*H + hglob)*W + w] = sp;

        // D': col=li=c, row=g*4+rr=h-in-tile -> accC[n][h][w][c]
        #pragma unroll
        for (int rr = 0; rr < 4; rr++) {
            int h2 = ht*16 + g*4 + rr;
            accCn[((long)h2*W + w)*16 + li] = (unsigned short)f2bf(acc[rr]);
        }
    }
}

// Row (W) attention as MFMA. Block = 2 rows; stages V (bf16) + K (fp32) in LDS.
// Wave (r, half) computes 6 D[16c x 16w] tiles via 6 k-chunks of 16x16x32 bf16 MFMA.
__global__ __launch_bounds__(256)
void row_attn_kernel(const float2* __restrict__ Qp, const float2* __restrict__ Kp,
                     const v4f* __restrict__ Vp,
                     const float* __restrict__ cmax, const float* __restrict__ rmax,
                     const unsigned short* __restrict__ accC, const float* __restrict__ sC,
                     const float* __restrict__ xres, long xn_s, long xc_s,
                     float* __restrict__ out, long on_s, long oc_s,
                     const float* __restrict__ gamma_p)
{
    __shared__ __align__(16) unsigned short Vl[2][16][200];  // bf16, pad 192->200
    __shared__ __align__(16) float          Kl[2][192][2];   // fp32 kx,ky

    const int chunk = (NIMG*(H/2)) / 8;   // 144
    int bid = blockIdx.x;
    int swz = (bid & 7)*chunk + (bid >> 3);
    int n   = swz / (H/2);
    int h0  = (swz - n*(H/2)) * 2;
    int tid = threadIdx.x;

    const float2* Qpn = Qp + n*PX;
    const float2* Kpn = Kp + n*PX;
    const v4f*    Vpn = Vp + (long)n*PX*4;

    #pragma unroll
    for (int i = 0; i < 6; i++) {
        int idx = i*256 + tid;            // 0..1535
        int rr  = idx / 768;
        int rem = idx - rr*768;
        int c4  = rem / 192;
        int w2  = rem - c4*192;
        v4f v = Vpn[((long)(h0+rr)*4 + c4)*W + w2];
        Vl[rr][c4*4+0][w2] = (unsigned short)f2bf(v[0]);
        Vl[rr][c4*4+1][w2] = (unsigned short)f2bf(v[1]);
        Vl[rr][c4*4+2][w2] = (unsigned short)f2bf(v[2]);
        Vl[rr][c4*4+3][w2] = (unsigned short)f2bf(v[3]);
    }
    if (tid < 192) {
        float2 ka = Kpn[(h0+0)*W + tid];
        float2 kb = Kpn[(h0+1)*W + tid];
        Kl[0][tid][0] = ka.x;  Kl[0][tid][1] = ka.y;
        Kl[1][tid][0] = kb.x;  Kl[1][tid][1] = kb.y;
    }

    int wv   = tid >> 6;        // 0..3
    int r    = wv >> 1;
    int half = wv & 1;
    int lane = tid & 63;
    int li   = lane & 15;
    int g    = lane >> 4;
    int h    = h0 + r;

    float r0 = rmax[n*2*H + h], r1 = rmax[n*2*H + H + h];
    float qx[6], qy[6], mW[6];
    #pragma unroll
    for (int t = 0; t < 6; t++) {
        int w = (half*6 + t)*16 + li;
        float2 qq = Qpn[h*W + w];
        float c0 = cmax[n*2*W + w], c1 = cmax[n*2*W + W + w];
        float lqx = qq.x * LOG2E, lqy = qq.y * LOG2E;
        qx[t] = lqx; qy[t] = lqy;
        mW[t] = fmaxf(fabsf(lqx)*c0 + fabsf(lqy)*c1, fabsf(lqx)*r0 + fabsf(lqy)*r1);
    }

    __syncthreads();

    v4f acc[6] = {};
    float sp[6] = {0.f,0.f,0.f,0.f,0.f,0.f};

    #pragma unroll
    for (int kc = 0; kc < 6; kc++) {
        int j0 = kc*32 + g*8;
        v8s af = *(const v8s*)&Vl[r][li][j0];
        const v4f* kp4 = (const v4f*)&Kl[r][j0][0];
        v4f k0 = kp4[0], k1 = kp4[1], k2 = kp4[2], k3 = kp4[3];
        float kxv[8] = {k0[0],k0[2],k1[0],k1[2],k2[0],k2[2],k3[0],k3[2]};
        float kyv[8] = {k0[1],k0[3],k1[1],k1[3],k2[1],k2[3],k3[1],k3[3]};
        #pragma unroll
        for (int t = 0; t < 6; t++) {
            v8s bf;
            float sl = sp[t];
            #pragma unroll
            for (int e = 0; e < 8; e++) {
                float ev = qx[t]*kxv[e] + qy[t]*kyv[e];
                float p = __builtin_amdgcn_exp2f(ev - mW[t]);
                sl += p;
                bf[e] = f2bf(p);
            }
            sp[t] = sl;
            acc[t] = __builtin_amdgcn_mfma_f32_16x16x32_bf16(af, bf, acc[t], 0, 0, 0);
        }
    }

    float gam = gamma_p[0];
    #pragma unroll
    for (int t = 0; t < 6; t++) {
        float s = sp[t];
        s += __shfl_xor(s, 16);
        s += __shfl_xor(s, 32);
        int w = (half*6 + t)*16 + li;
        float st = sC[((long)n*H + h)*W + w] + s;
        float inv = 1.0f / st;
        long po = (long)h*W + w;
        const unsigned short* cap = accC + (((long)n*H + h)*W + w)*16 + g*4;
        #pragma unroll
        for (int rr = 0; rr < 4; rr++) {
            int c = g*4 + rr;   // D: row = (lane>>4)*4 + reg
            float ac = bf2f(cap[rr]);
            float tot = (acc[t][rr] + ac) * inv;
            out[(long)n*on_s + (long)c*oc_s + po] =
                gam*tot + xres[(long)n*xn_s + (long)c*xc_s + po];
        }
    }
}

extern "C" void kernel_launch(void* const* d_in, const int* in_sizes, int n_in,
                              void* d_out, int out_size, void* d_ws, size_t ws_size,
                              hipStream_t stream) {
    const float* cost = (const float*)d_in[0];   // (1,16,24,96,192)
    const float* q_w  = (const float*)d_in[1];
    const float* q_b  = (const float*)d_in[2];
    const float* k_w  = (const float*)d_in[3];
    const float* k_b  = (const float*)d_in[4];
    const float* v_w  = (const float*)d_in[5];
    const float* v_b  = (const float*)d_in[6];
    const float* gamma= (const float*)d_in[7];
    float* out = (float*)d_out;
    float* ws  = (float*)d_ws;

    float2* Qp = (float2*)(ws + QP_OFF);
    float2* Kp = (float2*)(ws + KP_OFF);
    float4* Vp = (float4*)(ws + VP_OFF);
    float*  cm = ws + CMAX_OFF;
    float*  rm = ws + RMAX_OFF;
    float*  sC = ws + SC_OFF;
    unsigned short* aC = (unsigned short*)(ws + ACC_OFF);

    const int qkv_blocks = (NIMG*PX)/256;   // 1728
    const int col_blocks = NIMG*48;         // 1152 (4 columns per block)
    const int row_blocks = NIMG*(H/2);      // 1152

    // ---- pass 1: x = cost_volume [c][n][h][w] (n stride PX, c stride 24*PX) ----
    qkv_kernel<<<qkv_blocks, 256, 0, stream>>>(
        cost, (long)PX, (long)NIMG*PX,
        q_w, q_b, k_w, k_b, v_w, v_b, Qp, Kp, Vp);
    stats_kernel<<<NIMG, 192, 0, stream>>>(Kp, cm, rm);
    col_attn_kernel<<<col_blocks, 256, 0, stream>>>(
        Qp, Kp, (const v4f*)Vp, cm, rm, aC, sC);
    row_attn_kernel<<<row_blocks, 256, 0, stream>>>(
        Qp, Kp, (const v4f*)Vp, cm, rm, aC, sC,
        cost, (long)PX, (long)NIMG*PX,
        out,  (long)PX, (long)NIMG*PX,
        gamma);

    // ---- pass 2: x = d_out (same strides; per-thread same-element RMW is safe) ----
    qkv_kernel<<<qkv_blocks, 256, 0, stream>>>(
        out, (long)PX, (long)NIMG*PX,
        q_w, q_b, k_w, k_b, v_w, v_b, Qp, Kp, Vp);
    stats_kernel<<<NIMG, 192, 0, stream>>>(Kp, cm, rm);
    col_attn_kernel<<<col_blocks, 256, 0, stream>>>(
        Qp, Kp, (const v4f*)Vp, cm, rm, aC, sC);
    row_attn_kernel<<<row_blocks, 256, 0, stream>>>(
        Qp, Kp, (const v4f*)Vp, cm, rm, aC, sC,
        out, (long)PX, (long)NIMG*PX,
        out, (long)PX, (long)NIMG*PX,
        gamma);
}

// Round 19
// 156.322 us; speedup vs baseline: 3.4557x; 1.0636x over previous
//
#include <hip/hip_runtime.h>

#define C 16
#define NIMG 24
#define H 96
#define W 192
#define PX (H*W)            // 18432
#define LOG2E 1.44269504088896f

typedef float v2f  __attribute__((ext_vector_type(2)));
typedef float v4f  __attribute__((ext_vector_type(4)));
typedef short v8s  __attribute__((ext_vector_type(8)));

// workspace float offsets
#define QP_OFF 0                                // float2 [n][px]
#define KP_OFF (NIMG*PX*2)                      // float2 [n][px]
#define VB4_OFF (2*NIMG*PX*2)                   // ushort4 [n][h][c4][w] (bf16 x4ch)
#define VBP_OFF (VB4_OFF + NIMG*PX*C/2)         // ushort [n][h][c][w] (bf16 planar)
#define CMAX_OFF (VBP_OFF + NIMG*PX*C/2)        // 8847360
#define RMAX_OFF (CMAX_OFF + NIMG*2*W)          // 8856576
#define SC_OFF   (RMAX_OFF + NIMG*2*H)          // 8861184  float s_col [n][h][w]
#define ACC_OFF  (SC_OFF + NIMG*PX)             // 9303552  ushort accC [n][h][w][c]

__device__ __forceinline__ unsigned short f2bf(float x) {
    union { float f; unsigned u; } v; v.f = x;
    unsigned r = v.u + 0x7fffu + ((v.u >> 16) & 1u);   // RNE
    return (unsigned short)(r >> 16);
}
__device__ __forceinline__ float bf2f(unsigned short u) {
    union { unsigned u; float f; } v; v.u = ((unsigned)u) << 16;
    return v.f;
}

__global__ __launch_bounds__(256)
void qkv_kernel(const float* __restrict__ x, long xn_s, long xc_s,
                const float* __restrict__ qw, const float* __restrict__ qb,
                const float* __restrict__ kw, const float* __restrict__ kb,
                const float* __restrict__ vw, const float* __restrict__ vb,
                float2* __restrict__ Qp, float2* __restrict__ Kp,
                ushort4* __restrict__ Vb4, unsigned short* __restrict__ Vbp,
                float* __restrict__ cmax_zero)
{
    __shared__ float wq[2*C+2], wk[2*C+2], wv[C*C+C];
    int tid = threadIdx.x;
    if (tid < 2*C) { wq[tid] = qw[tid]; wk[tid] = kw[tid]; }
    if (tid < 2)   { wq[2*C+tid] = qb[tid]; wk[2*C+tid] = kb[tid]; }
    if (tid < C*C) wv[tid] = vw[tid];
    if (tid < C)   wv[C*C+tid] = vb[tid];

    // fold cmax zero-init into the first 36 blocks (consumed by stats kernel)
    if (blockIdx.x < 36) {
        int zi = blockIdx.x*256 + tid;
        if (zi < NIMG*2*W) cmax_zero[zi] = 0.0f;
    }
    __syncthreads();

    int id = blockIdx.x*256 + tid;        // 0 .. 442367
    int n  = id / PX;
    int p  = id - n*PX;
    int h  = p / W;
    int w  = p - h*W;
    const float* xp = x + (long)n*xn_s + p;

    float xv[C];
    #pragma unroll
    for (int c = 0; c < C; c++) xv[c] = xp[(long)c*xc_s];

    float q0 = wq[2*C], q1 = wq[2*C+1];
    float k0 = wk[2*C], k1 = wk[2*C+1];
    #pragma unroll
    for (int c = 0; c < C; c++) {
        q0 += wq[c]*xv[c];   q1 += wq[C+c]*xv[c];
        k0 += wk[c]*xv[c];   k1 += wk[C+c]*xv[c];
    }
    Qp[id] = make_float2(q0, q1);
    Kp[id] = make_float2(k0, k1);

    float vv[C];
    #pragma unroll
    for (int o = 0; o < C; o++) {
        float a = wv[C*C+o];
        #pragma unroll
        for (int c = 0; c < C; c++) a += wv[o*C+c]*xv[c];
        vv[o] = a;
    }
    unsigned short vb16[C];
    #pragma unroll
    for (int o = 0; o < C; o++) vb16[o] = f2bf(vv[o]);

    // interleaved [n][h][c4][w] (ushort4) for col staging
    #pragma unroll
    for (int c4 = 0; c4 < 4; c4++) {
        ushort4 u;
        u.x = vb16[c4*4+0]; u.y = vb16[c4*4+1];
        u.z = vb16[c4*4+2]; u.w = vb16[c4*4+3];
        Vb4[(((long)n*H + h)*4 + c4)*W + w] = u;
    }
    // planar [n][h][c][w] for row fragment loads
    #pragma unroll
    for (int o = 0; o < C; o++)
        Vbp[(((long)n*H + h)*16 + o)*W + w] = vb16[o];
}

// 96 blocks: (n, h-slice of 24 rows). cmax via uint atomicMax, rmax direct.
__global__ __launch_bounds__(192)
void stats_kernel(const float2* __restrict__ Kp,
                  float* __restrict__ cmax, float* __restrict__ rmax)
{
    int bid = blockIdx.x;
    int n   = bid >> 2;
    int h0  = (bid & 3) * 24;
    int tid = threadIdx.x;
    const float2* Kpn = Kp + n*PX;

    // column max over this 24-row slice (w = tid, coalesced)
    float c0 = 0.f, c1 = 0.f;
    #pragma unroll 4
    for (int h = 0; h < 24; h++) {
        float2 k = Kpn[(h0+h)*W + tid];
        c0 = fmaxf(c0, fabsf(k.x));
        c1 = fmaxf(c1, fabsf(k.y));
    }
    atomicMax((unsigned*)&cmax[n*2*W + tid],     __float_as_uint(c0));
    atomicMax((unsigned*)&cmax[n*2*W + W + tid], __float_as_uint(c1));

    // row max: 8 threads per row, 24 w each, shuffle-merged
    int r = tid >> 3, seg = tid & 7;
    float r0 = 0.f, r1 = 0.f;
    const float2* kr = Kpn + (h0+r)*W + seg*24;
    #pragma unroll 4
    for (int j = 0; j < 24; j++) {
        float2 k = kr[j];
        r0 = fmaxf(r0, fabsf(k.x));
        r1 = fmaxf(r1, fabsf(k.y));
    }
    r0 = fmaxf(r0, __shfl_xor(r0, 1)); r0 = fmaxf(r0, __shfl_xor(r0, 2)); r0 = fmaxf(r0, __shfl_xor(r0, 4));
    r1 = fmaxf(r1, __shfl_xor(r1, 1)); r1 = fmaxf(r1, __shfl_xor(r1, 2)); r1 = fmaxf(r1, __shfl_xor(r1, 4));
    if (seg == 0) {
        rmax[n*2*H + h0 + r]     = r0;
        rmax[n*2*H + H + h0 + r] = r1;
    }
}

// Column (H) attention as MFMA (R18 structure, bf16 V staging reads).
#define VT_WS 1672   // per-w Vt stride in ushorts: 16*104 + 8 pad
__global__ __launch_bounds__(256)
void col_attn_kernel(const float2* __restrict__ Qp, const float2* __restrict__ Kp,
                     const ushort4* __restrict__ Vb4,
                     const float* __restrict__ cmax, const float* __restrict__ rmax,
                     unsigned short* __restrict__ accC, float* __restrict__ sC)
{
    __shared__ unsigned short Vt[4*VT_WS];      // V^T: [wl][c][j] bf16, j-pad 104
    __shared__ unsigned short Ks[4*2*96];       // K:   [wl][ch][j] bf16
    __shared__ float2         Qs[4*96];         // q (log2-scaled): [wl][h]
    __shared__ float          Ms[4*96];         // shift bound m:   [wl][h]

    const int chunk = (NIMG*48) / 8;            // 144 ; 1152 % 8 == 0
    int bid = blockIdx.x;
    int swz = (bid & 7)*chunk + (bid >> 3);
    int n   = swz / 48;
    int wg  = swz - n*48;
    int w0  = wg*4;
    int tid = threadIdx.x;

    const float2* Qpn = Qp + n*PX;
    const float2* Kpn = Kp + n*PX;
    const ushort4* Vbn = Vb4 + (long)n*PX*4;

    // ---- stage V^T (1536 ushort4, 6/thread) ----
    #pragma unroll
    for (int i = 0; i < 6; i++) {
        int idx = i*256 + tid;        // 0..1535
        int wl  = idx & 3;
        int c4  = (idx >> 2) & 3;
        int j   = idx >> 4;           // 0..95
        ushort4 v = Vbn[((long)j*4 + c4)*W + w0 + wl];
        int b = wl*VT_WS + (c4*4)*104 + j;
        Vt[b        ] = v.x;
        Vt[b + 104  ] = v.y;
        Vt[b + 208  ] = v.z;
        Vt[b + 312  ] = v.w;
    }
    // ---- stage K (384 float2 -> bf16) ----
    #pragma unroll
    for (int i = 0; i < 2; i++) {
        int idx = i*256 + tid;
        if (idx < 384) {
            int wl = idx & 3;
            int j  = idx >> 2;
            float2 kk = Kpn[j*W + w0 + wl];
            Ks[wl*192 + j]      = f2bf(kk.x);
            Ks[wl*192 + 96 + j] = f2bf(kk.y);
        }
    }
    // ---- stage Q (log2 domain) + m bound ----
    #pragma unroll
    for (int i = 0; i < 2; i++) {
        int idx = i*256 + tid;
        if (idx < 384) {
            int wl = idx & 3;
            int h  = idx >> 2;
            int w  = w0 + wl;
            float2 qq = Qpn[h*W + w];
            float qx = qq.x * LOG2E, qy = qq.y * LOG2E;
            float c0 = cmax[n*2*W + w], c1 = cmax[n*2*W + W + w];
            float r0 = rmax[n*2*H + h], r1 = rmax[n*2*H + H + h];
            float ax = fabsf(qx), ay = fabsf(qy);
            Qs[wl*96 + h] = make_float2(qx, qy);
            Ms[wl*96 + h] = fmaxf(ax*c0 + ay*c1, ax*r0 + ay*r1);
        }
    }
    __syncthreads();

    int wl   = tid >> 6;        // wave id 0..3 = column
    int lane = tid & 63;
    int li   = lane & 15;
    int g    = lane >> 4;
    int w    = w0 + wl;
    unsigned short* accCn = accC + (long)n*PX*16;

    #pragma unroll
    for (int ht = 0; ht < 6; ht++) {
        int hglob = ht*16 + li;
        float2 q = Qs[wl*96 + hglob];
        float  m = Ms[wl*96 + hglob];

        v4f acc = {};
        float sp = 0.f;
        #pragma unroll
        for (int kc = 0; kc < 3; kc++) {
            int j0 = kc*32 + g*8;
            v8s bv = *(const v8s*)&Vt[wl*VT_WS + li*104 + j0];
            v8s kxv = *(const v8s*)&Ks[wl*192 + j0];
            v8s kyv = *(const v8s*)&Ks[wl*192 + 96 + j0];
            v8s af;
            #pragma unroll
            for (int e = 0; e < 8; e++) {
                float e2 = bf2f((unsigned short)kxv[e])*q.x
                         + bf2f((unsigned short)kyv[e])*q.y - m;
                float p = __builtin_amdgcn_exp2f(e2);
                p = (j0 + e == hglob) ? 0.0f : p;
                sp += p;
                af[e] = (short)f2bf(p);
            }
            acc = __builtin_amdgcn_mfma_f32_16x16x32_bf16(af, bv, acc, 0, 0, 0);
        }
        sp += __shfl_xor(sp, 16);
        sp += __shfl_xor(sp, 32);
        if (lane < 16)
            sC[((long)n*H + hglob)*W + w] = sp;

        #pragma unroll
        for (int rr = 0; rr < 4; rr++) {
            int h2 = ht*16 + g*4 + rr;
            accCn[((long)h2*W + w)*16 + li] = f2bf(acc[rr]);
        }
    }
}

// Row (W) attention as MFMA, LDS-free: A-fragments from planar bf16 V (global,
// 16B/lane contiguous), K from Kp (L2-hot 64B/lane). No staging, no barrier.
__global__ __launch_bounds__(256)
void row_attn_kernel(const float2* __restrict__ Qp, const float2* __restrict__ Kp,
                     const unsigned short* __restrict__ Vbp,
                     const float* __restrict__ cmax, const float* __restrict__ rmax,
                     const unsigned short* __restrict__ accC, const float* __restrict__ sC,
                     const float* __restrict__ xres, long xn_s, long xc_s,
                     float* __restrict__ out, long on_s, long oc_s,
                     const float* __restrict__ gamma_p)
{
    const int chunk = (NIMG*(H/2)) / 8;   // 144
    int bid = blockIdx.x;
    int swz = (bid & 7)*chunk + (bid >> 3);
    int n   = swz / (H/2);
    int h0  = (swz - n*(H/2)) * 2;
    int tid = threadIdx.x;

    const float2* Qpn = Qp + n*PX;
    const float*  Kf  = (const float*)(Kp + n*PX);
    const unsigned short* Vrn = Vbp + (long)n*PX*16;   // [h][c][w]

    int wv   = tid >> 6;        // 0..3
    int r    = wv >> 1;
    int half = wv & 1;
    int lane = tid & 63;
    int li   = lane & 15;
    int g    = lane >> 4;
    int h    = h0 + r;

    float r0 = rmax[n*2*H + h], r1 = rmax[n*2*H + H + h];
    float qx[6], qy[6], mW[6];
    #pragma unroll
    for (int t = 0; t < 6; t++) {
        int w = (half*6 + t)*16 + li;
        float2 qq = Qpn[h*W + w];
        float c0 = cmax[n*2*W + w], c1 = cmax[n*2*W + W + w];
        float lqx = qq.x * LOG2E, lqy = qq.y * LOG2E;
        qx[t] = lqx; qy[t] = lqy;
        mW[t] = fmaxf(fabsf(lqx)*c0 + fabsf(lqy)*c1, fabsf(lqx)*r0 + fabsf(lqy)*r1);
    }

    v4f acc[6] = {};
    float sp[6] = {0.f,0.f,0.f,0.f,0.f,0.f};

    const unsigned short* Vrow = Vrn + (long)h*16*W + (long)li*W;
    const float*          Krow = Kf + (long)h*W*2;

    #pragma unroll
    for (int kc = 0; kc < 6; kc++) {
        int j0 = kc*32 + g*8;
        v8s af = *(const v8s*)(Vrow + j0);                 // 16B contiguous
        const v4f* kp4 = (const v4f*)(Krow + j0*2);
        v4f k0 = kp4[0], k1 = kp4[1], k2 = kp4[2], k3 = kp4[3];
        float kxv[8] = {k0[0],k0[2],k1[0],k1[2],k2[0],k2[2],k3[0],k3[2]};
        float kyv[8] = {k0[1],k0[3],k1[1],k1[3],k2[1],k2[3],k3[1],k3[3]};
        #pragma unroll
        for (int t = 0; t < 6; t++) {
            v8s bf;
            float sl = sp[t];
            #pragma unroll
            for (int e = 0; e < 8; e++) {
                float ev = qx[t]*kxv[e] + qy[t]*kyv[e];
                float p = __builtin_amdgcn_exp2f(ev - mW[t]);
                sl += p;
                bf[e] = (short)f2bf(p);
            }
            sp[t] = sl;
            acc[t] = __builtin_amdgcn_mfma_f32_16x16x32_bf16(af, bf, acc[t], 0, 0, 0);
        }
    }

    float gam = gamma_p[0];
    #pragma unroll
    for (int t = 0; t < 6; t++) {
        float s = sp[t];
        s += __shfl_xor(s, 16);
        s += __shfl_xor(s, 32);
        int w = (half*6 + t)*16 + li;
        float st = sC[((long)n*H + h)*W + w] + s;
        float inv = 1.0f / st;
        long po = (long)h*W + w;
        const unsigned short* cap = accC + (((long)n*H + h)*W + w)*16 + g*4;
        #pragma unroll
        for (int rr = 0; rr < 4; rr++) {
            int c = g*4 + rr;   // D: row = (lane>>4)*4 + reg
            float ac = bf2f(cap[rr]);
            float tot = (acc[t][rr] + ac) * inv;
            out[(long)n*on_s + (long)c*oc_s + po] =
                gam*tot + xres[(long)n*xn_s + (long)c*xc_s + po];
        }
    }
}

extern "C" void kernel_launch(void* const* d_in, const int* in_sizes, int n_in,
                              void* d_out, int out_size, void* d_ws, size_t ws_size,
                              hipStream_t stream) {
    const float* cost = (const float*)d_in[0];   // (1,16,24,96,192)
    const float* q_w  = (const float*)d_in[1];
    const float* q_b  = (const float*)d_in[2];
    const float* k_w  = (const float*)d_in[3];
    const float* k_b  = (const float*)d_in[4];
    const float* v_w  = (const float*)d_in[5];
    const float* v_b  = (const float*)d_in[6];
    const float* gamma= (const float*)d_in[7];
    float* out = (float*)d_out;
    float* ws  = (float*)d_ws;

    float2*  Qp = (float2*)(ws + QP_OFF);
    float2*  Kp = (float2*)(ws + KP_OFF);
    ushort4* Vb4 = (ushort4*)(ws + VB4_OFF);
    unsigned short* Vbp = (unsigned short*)(ws + VBP_OFF);
    float*   cm = ws + CMAX_OFF;
    float*   rm = ws + RMAX_OFF;
    float*   sC = ws + SC_OFF;
    unsigned short* aC = (unsigned short*)(ws + ACC_OFF);

    const int qkv_blocks  = (NIMG*PX)/256;   // 1728
    const int stat_blocks = NIMG*4;          // 96
    const int col_blocks  = NIMG*48;         // 1152 (4 columns per block)
    const int row_blocks  = NIMG*(H/2);      // 1152

    // ---- pass 1: x = cost_volume [c][n][h][w] (n stride PX, c stride 24*PX) ----
    qkv_kernel<<<qkv_blocks, 256, 0, stream>>>(
        cost, (long)PX, (long)NIMG*PX,
        q_w, q_b, k_w, k_b, v_w, v_b, Qp, Kp, Vb4, Vbp, cm);
    stats_kernel<<<stat_blocks, 192, 0, stream>>>(Kp, cm, rm);
    col_attn_kernel<<<col_blocks, 256, 0, stream>>>(
        Qp, Kp, Vb4, cm, rm, aC, sC);
    row_attn_kernel<<<row_blocks, 256, 0, stream>>>(
        Qp, Kp, Vbp, cm, rm, aC, sC,
        cost, (long)PX, (long)NIMG*PX,
        out,  (long)PX, (long)NIMG*PX,
        gamma);

    // ---- pass 2: x = d_out (same strides; per-thread same-element RMW is safe) ----
    qkv_kernel<<<qkv_blocks, 256, 0, stream>>>(
        out, (long)PX, (long)NIMG*PX,
        q_w, q_b, k_w, k_b, v_w, v_b, Qp, Kp, Vb4, Vbp, cm);
    stats_kernel<<<stat_blocks, 192, 0, stream>>>(Kp, cm, rm);
    col_attn_kernel<<<col_blocks, 256, 0, stream>>>(
        Qp, Kp, Vb4, cm, rm, aC, sC);
    row_attn_kernel<<<row_blocks, 256, 0, stream>>>(
        Qp, Kp, Vbp, cm, rm, aC, sC,
        out, (long)PX, (long)NIMG*PX,
        out, (long)PX, (long)NIMG*PX,
        gamma);
}